// Round 4
// baseline (1247.408 us; speedup 1.0000x reference)
//
#include <hip/hip_runtime.h>

#define N_NODES 50000
#define N_EDGES 600000
#define D 128
#define NBKT 782            // ceil(50000/64) buckets of 64 rows
#define NCHUNK 8            // XCD-locality sub-partitions
#define NCNT (2 * NBKT * NCHUNK)  // 12512 counters (2 supports)
#define NBSTART (2 * NBKT + 1)    // 1565
#define EDGE_BLOCKS 2344    // ceil(600000/256)

// ============================================================================
// Fused GEMM: preb[sup][n][d] = bf16( sum_k x[n][k] * W{sup}[k][d] )
// 64 nodes/block, 256 threads: thread = 8 nodes x 4 dims x 2 supports.
// ============================================================================
__device__ __forceinline__ unsigned short f2bf(float f) {
  unsigned u = __float_as_uint(f);
  return (unsigned short)((u + 0x7FFFu + ((u >> 16) & 1u)) >> 16);
}

__global__ __launch_bounds__(256) void gemm2_kernel(
    const float* __restrict__ x, const float* __restrict__ W0,
    const float* __restrict__ W1, unsigned short* __restrict__ preb) {
  const int tid = threadIdx.x;
  const int nloc = (tid >> 5) << 3;  // local node base 0,8,...,56
  const int d4 = (tid & 31) << 2;    // dim base
  const int nbase = blockIdx.x * 64;

  __shared__ float xs[64][D];
  {
    float4* xs4 = (float4*)(&xs[0][0]);
    const float4* xg4 = (const float4*)x;
#pragma unroll
    for (int i = 0; i < 8; ++i) {
      const int idx = tid + i * 256;
      const int row = nbase + (idx >> 5);
      xs4[idx] = (row < N_NODES) ? xg4[(size_t)row * 32 + (idx & 31)]
                                 : make_float4(0.f, 0.f, 0.f, 0.f);
    }
  }
  __syncthreads();

  float4 a0[8], a1[8];
#pragma unroll
  for (int i = 0; i < 8; ++i) {
    a0[i] = make_float4(0.f, 0.f, 0.f, 0.f);
    a1[i] = make_float4(0.f, 0.f, 0.f, 0.f);
  }

  for (int k = 0; k < D; k += 2) {
    const float4 w00 = *(const float4*)(W0 + (k + 0) * D + d4);
    const float4 w01 = *(const float4*)(W0 + (k + 1) * D + d4);
    const float4 w10 = *(const float4*)(W1 + (k + 0) * D + d4);
    const float4 w11 = *(const float4*)(W1 + (k + 1) * D + d4);
#pragma unroll
    for (int i = 0; i < 8; ++i) {
      const float x0 = xs[nloc + i][k];
      const float x1 = xs[nloc + i][k + 1];
      a0[i].x = fmaf(x0, w00.x, a0[i].x); a0[i].y = fmaf(x0, w00.y, a0[i].y);
      a0[i].z = fmaf(x0, w00.z, a0[i].z); a0[i].w = fmaf(x0, w00.w, a0[i].w);
      a0[i].x = fmaf(x1, w01.x, a0[i].x); a0[i].y = fmaf(x1, w01.y, a0[i].y);
      a0[i].z = fmaf(x1, w01.z, a0[i].z); a0[i].w = fmaf(x1, w01.w, a0[i].w);
      a1[i].x = fmaf(x0, w10.x, a1[i].x); a1[i].y = fmaf(x0, w10.y, a1[i].y);
      a1[i].z = fmaf(x0, w10.z, a1[i].z); a1[i].w = fmaf(x0, w10.w, a1[i].w);
      a1[i].x = fmaf(x1, w11.x, a1[i].x); a1[i].y = fmaf(x1, w11.y, a1[i].y);
      a1[i].z = fmaf(x1, w11.z, a1[i].z); a1[i].w = fmaf(x1, w11.w, a1[i].w);
    }
  }

#pragma unroll
  for (int i = 0; i < 8; ++i) {
    const int n = nbase + nloc + i;
    if (n < N_NODES) {
      ushort4 p0, p1;
      p0.x = f2bf(a0[i].x); p0.y = f2bf(a0[i].y);
      p0.z = f2bf(a0[i].z); p0.w = f2bf(a0[i].w);
      p1.x = f2bf(a1[i].x); p1.y = f2bf(a1[i].y);
      p1.z = f2bf(a1[i].z); p1.w = f2bf(a1[i].w);
      *(ushort4*)(preb + (size_t)n * D + d4) = p0;
      *(ushort4*)(preb + (size_t)(N_NODES + n) * D + d4) = p1;
    }
  }
}

// ============================================================================
// Bucket build: hist -> single-block scan -> chunk-local scatter
// counter index: (sup*NBKT + bucket)*NCHUNK + chunk,  chunk = blockIdx.x & 7
// ============================================================================
__global__ __launch_bounds__(256) void hist_kernel(
    const int* __restrict__ rows0, const int* __restrict__ rows1,
    int* __restrict__ cnt) {
  const int e = blockIdx.x * 256 + threadIdx.x;
  if (e >= N_EDGES) return;
  const int sup = blockIdx.y;
  const int r = (sup == 0 ? rows0 : rows1)[e];
  const int idx = ((sup * NBKT + (r >> 6)) << 3) + (blockIdx.x & 7);
  atomicAdd(&cnt[idx], 1);
}

__global__ __launch_bounds__(1024) void scan_kernel(
    const int* __restrict__ cnt, int* __restrict__ basefill,
    int* __restrict__ bstart) {
  __shared__ int sums[1024];
  const int t = threadIdx.x;
  const int base_i = t * 13;
  int loc[13];
  int s = 0;
#pragma unroll
  for (int k = 0; k < 13; ++k) {
    const int g = base_i + k;
    const int v = (g < NCNT) ? cnt[g] : 0;
    loc[k] = v;
    s += v;
  }
  sums[t] = s;
  __syncthreads();
  for (int off = 1; off < 1024; off <<= 1) {
    const int v = sums[t];
    const int u = (t >= off) ? sums[t - off] : 0;
    __syncthreads();
    sums[t] = v + u;
    __syncthreads();
  }
  int excl = (t == 0) ? 0 : sums[t - 1];
#pragma unroll
  for (int k = 0; k < 13; ++k) {
    const int g = base_i + k;
    if (g < NCNT) {
      basefill[g] = excl;
      if ((g & 7) == 0) bstart[g >> 3] = excl;
      excl += loc[k];
    }
  }
  if (t == 1023) bstart[2 * NBKT] = 2 * N_EDGES;
}

// cv entry: x = col | (row%64 << 16), y = bits(val)
__global__ __launch_bounds__(256) void fill_kernel(
    const int* __restrict__ rows0, const int* __restrict__ cols0,
    const float* __restrict__ vals0, const int* __restrict__ rows1,
    const int* __restrict__ cols1, const float* __restrict__ vals1,
    int* __restrict__ basefill, int2* __restrict__ cv) {
  const int e = blockIdx.x * 256 + threadIdx.x;
  if (e >= N_EDGES) return;
  const int sup = blockIdx.y;
  const int* rows = (sup == 0) ? rows0 : rows1;
  const int* cols = (sup == 0) ? cols0 : cols1;
  const float* vals = (sup == 0) ? vals0 : vals1;
  const int r = rows[e];
  const int idx = ((sup * NBKT + (r >> 6)) << 3) + (blockIdx.x & 7);
  const int p = atomicAdd(&basefill[idx], 1);
  cv[p] = make_int2(cols[e] | ((r & 63) << 16), __float_as_int(vals[e]));
}

// ============================================================================
// SpMM: one block per 64-row bucket; LDS fp32 accumulator (32 KB);
// both supports + bias + relu fused. Edge-parallel: wave takes 64-edge
// groups, broadcasts (col,rloc,val) via shfl, 64 lanes x 2 dims bf16 gather,
// ds_add_f32 accumulate.
// ============================================================================
__global__ __launch_bounds__(512) void spmm_bucket_kernel(
    const int* __restrict__ bstart, const int2* __restrict__ cv,
    const unsigned short* __restrict__ preb, const float* __restrict__ bias,
    float* __restrict__ out) {
  __shared__ float acc[64 * D];  // 32 KB
  const int tid = threadIdx.x;
  const int lane = tid & 63;
  const int wv = tid >> 6;  // 8 waves
  const int b = blockIdx.x;

  {
    float4* a4 = (float4*)acc;
#pragma unroll
    for (int i = 0; i < 4; ++i) a4[tid + i * 512] = make_float4(0.f, 0.f, 0.f, 0.f);
  }
  __syncthreads();

#pragma unroll
  for (int sup = 0; sup < 2; ++sup) {
    const int s = bstart[sup * NBKT + b];
    const int e = bstart[sup * NBKT + b + 1];
    const unsigned short* pb = preb + (size_t)sup * N_NODES * D;
    for (int j = s + wv * 64; j < e; j += 8 * 64) {
      const int nb = min(64, e - j);
      int2 ev = make_int2(0, 0);
      if (lane < nb) ev = cv[j + lane];
      for (int t = 0; t < nb; ++t) {
        const int cx = __shfl(ev.x, t);
        const float v = __int_as_float(__shfl(ev.y, t));
        const int c = cx & 0xFFFF;
        const int rloc = cx >> 16;
        const ushort2 pk =
            *(const ushort2*)(pb + (size_t)c * D + (lane << 1));
        const float p0 = __uint_as_float((unsigned)pk.x << 16);
        const float p1 = __uint_as_float((unsigned)pk.y << 16);
        float* ap = &acc[rloc * D + (lane << 1)];
        atomicAdd(ap + 0, v * p0);
        atomicAdd(ap + 1, v * p1);
      }
    }
  }
  __syncthreads();

  // epilogue: out[row] = relu(acc + bias)
  const int row0 = b * 64;
  const float4* accf4 = (const float4*)acc;
  const float4* bias4 = (const float4*)bias;
  for (int idx = tid; idx < 64 * (D / 4); idx += 512) {
    const int r = row0 + (idx >> 5);
    if (r >= N_NODES) break;
    float4 a = accf4[idx];
    const float4 bb = bias4[idx & 31];
    a.x = fmaxf(a.x + bb.x, 0.f);
    a.y = fmaxf(a.y + bb.y, 0.f);
    a.z = fmaxf(a.z + bb.z, 0.f);
    a.w = fmaxf(a.w + bb.w, 0.f);
    *(float4*)(out + (size_t)r * D + ((idx & 31) << 2)) = a;
  }
}

// ============================================================================
// Fallback: fp32 gemm + atomic scatter (used only if workspace too small)
// ============================================================================
__global__ __launch_bounds__(256) void gemm_f32_kernel(
    const float* __restrict__ x, const float* __restrict__ W,
    float* __restrict__ pre) {
  const int tid = threadIdx.x;
  const int nloc = (tid >> 5) << 3;
  const int d4 = (tid & 31) << 2;
  const int nbase = blockIdx.x * 64;
  __shared__ float xs[64][D];
  {
    float4* xs4 = (float4*)(&xs[0][0]);
    const float4* xg4 = (const float4*)x;
#pragma unroll
    for (int i = 0; i < 8; ++i) {
      const int idx = tid + i * 256;
      const int row = nbase + (idx >> 5);
      xs4[idx] = (row < N_NODES) ? xg4[(size_t)row * 32 + (idx & 31)]
                                 : make_float4(0.f, 0.f, 0.f, 0.f);
    }
  }
  __syncthreads();
  float4 acc[8];
#pragma unroll
  for (int i = 0; i < 8; ++i) acc[i] = make_float4(0.f, 0.f, 0.f, 0.f);
  for (int k = 0; k < D; ++k) {
    const float4 w = *(const float4*)(W + k * D + d4);
#pragma unroll
    for (int i = 0; i < 8; ++i) {
      const float xv = xs[nloc + i][k];
      acc[i].x = fmaf(xv, w.x, acc[i].x);
      acc[i].y = fmaf(xv, w.y, acc[i].y);
      acc[i].z = fmaf(xv, w.z, acc[i].z);
      acc[i].w = fmaf(xv, w.w, acc[i].w);
    }
  }
#pragma unroll
  for (int i = 0; i < 8; ++i) {
    const int n = nbase + nloc + i;
    if (n < N_NODES) *(float4*)(pre + (size_t)n * D + d4) = acc[i];
  }
}

__global__ __launch_bounds__(256) void spmm_scatter_kernel(
    const int* __restrict__ rows, const int* __restrict__ cols,
    const float* __restrict__ vals, const float* __restrict__ pre,
    float* __restrict__ out) {
  const long long idx = (long long)blockIdx.x * blockDim.x + threadIdx.x;
  const int e = (int)(idx >> 6);
  if (e >= N_EDGES) return;
  const int dd = ((int)idx & 63) << 1;
  const int r = rows[e];
  const int c = cols[e];
  const float v = vals[e];
  const float2 p = *(const float2*)(pre + (size_t)c * D + dd);
  float* outp = out + (size_t)r * D + dd;
  atomicAdd(outp + 0, v * p.x);
  atomicAdd(outp + 1, v * p.y);
}

__global__ __launch_bounds__(256) void bias_relu_kernel(
    float* __restrict__ out, const float* __restrict__ b) {
  const int idx = blockIdx.x * blockDim.x + threadIdx.x;
  float4 v = ((float4*)out)[idx];
  const float4 bb = ((const float4*)b)[idx & 31];
  v.x = fmaxf(v.x + bb.x, 0.f);
  v.y = fmaxf(v.y + bb.y, 0.f);
  v.z = fmaxf(v.z + bb.z, 0.f);
  v.w = fmaxf(v.w + bb.w, 0.f);
  ((float4*)out)[idx] = v;
}

extern "C" void kernel_launch(void* const* d_in, const int* in_sizes, int n_in,
                              void* d_out, int out_size, void* d_ws,
                              size_t ws_size, hipStream_t stream) {
  const float* x = (const float*)d_in[0];
  const float* W0 = (const float*)d_in[1];
  const float* W1 = (const float*)d_in[2];
  const float* b = (const float*)d_in[3];
  const int* rows0 = (const int*)d_in[4];
  const int* cols0 = (const int*)d_in[5];
  const float* vals0 = (const float*)d_in[6];
  const int* rows1 = (const int*)d_in[7];
  const int* cols1 = (const int*)d_in[8];
  const float* vals1 = (const float*)d_in[9];
  float* out = (float*)d_out;

  auto align_up = [](size_t v) { return (v + 255) & ~(size_t)255; };
  const size_t PREB = align_up((size_t)2 * N_NODES * D * 2);  // 25.6 MB bf16
  const size_t CV = align_up((size_t)2 * N_EDGES * 8);        // 9.6 MB
  const size_t CNT = align_up((size_t)NCNT * 4);
  const size_t BFILL = align_up((size_t)NCNT * 4);
  const size_t BSTART = align_up((size_t)NBSTART * 4);
  const size_t NEED = PREB + CV + CNT + BFILL + BSTART;

  char* wsc = (char*)d_ws;

  if (ws_size >= NEED) {
    unsigned short* preb = (unsigned short*)wsc;
    int2* cv = (int2*)(wsc + PREB);
    int* cnt = (int*)(wsc + PREB + CV);
    int* basefill = (int*)(wsc + PREB + CV + CNT);
    int* bstart = (int*)(wsc + PREB + CV + CNT + BFILL);

    hipMemsetAsync(cnt, 0, (size_t)NCNT * 4, stream);
    hist_kernel<<<dim3(EDGE_BLOCKS, 2), 256, 0, stream>>>(rows0, rows1, cnt);
    scan_kernel<<<1, 1024, 0, stream>>>(cnt, basefill, bstart);
    fill_kernel<<<dim3(EDGE_BLOCKS, 2), 256, 0, stream>>>(
        rows0, cols0, vals0, rows1, cols1, vals1, basefill, cv);
    gemm2_kernel<<<NBKT, 256, 0, stream>>>(x, W0, W1, preb);
    spmm_bucket_kernel<<<NBKT, 512, 0, stream>>>(bstart, cv, preb, b, out);
  } else {
    float* pre = (float*)wsc;  // 25.6 MB fp32
    hipMemsetAsync(d_out, 0, (size_t)N_NODES * D * 4, stream);
    const int scat_blocks = (N_EDGES * 64 + 255) / 256;
    gemm_f32_kernel<<<NBKT, 256, 0, stream>>>(x, W0, pre);
    spmm_scatter_kernel<<<scat_blocks, 256, 0, stream>>>(rows0, cols0, vals0,
                                                         pre, out);
    gemm_f32_kernel<<<NBKT, 256, 0, stream>>>(x, W1, pre);
    spmm_scatter_kernel<<<scat_blocks, 256, 0, stream>>>(rows1, cols1, vals1,
                                                         pre, out);
    bias_relu_kernel<<<(N_NODES * D / 4) / 256, 256, 0, stream>>>(out, b);
  }
}

// Round 5
// 274.670 us; speedup vs baseline: 4.5415x; 4.5415x over previous
//
#include <hip/hip_runtime.h>

#define N_NODES 50000
#define N_EDGES 600000
#define D 128
#define NBKT 782            // ceil(50000/64) buckets of 64 rows
#define NCNT (2 * NBKT * 8) // 12512 counters (2 supports x 8 chunks)
#define NBSTART (2 * NBKT + 1)
#define EDGE_BLOCKS 2344    // ceil(600000/256)

// ============================================================================
// Fused GEMM: preb[sup][n][d] = bf16( sum_k x[n][k] * W{sup}[k][d] )
// ============================================================================
__device__ __forceinline__ unsigned short f2bf(float f) {
  unsigned u = __float_as_uint(f);
  return (unsigned short)((u + 0x7FFFu + ((u >> 16) & 1u)) >> 16);
}

__global__ __launch_bounds__(256) void gemm2_kernel(
    const float* __restrict__ x, const float* __restrict__ W0,
    const float* __restrict__ W1, unsigned short* __restrict__ preb) {
  const int tid = threadIdx.x;
  const int nloc = (tid >> 5) << 3;
  const int d4 = (tid & 31) << 2;
  const int nbase = blockIdx.x * 64;

  __shared__ float xs[64][D];
  {
    float4* xs4 = (float4*)(&xs[0][0]);
    const float4* xg4 = (const float4*)x;
#pragma unroll
    for (int i = 0; i < 8; ++i) {
      const int idx = tid + i * 256;
      const int row = nbase + (idx >> 5);
      xs4[idx] = (row < N_NODES) ? xg4[(size_t)row * 32 + (idx & 31)]
                                 : make_float4(0.f, 0.f, 0.f, 0.f);
    }
  }
  __syncthreads();

  float4 a0[8], a1[8];
#pragma unroll
  for (int i = 0; i < 8; ++i) {
    a0[i] = make_float4(0.f, 0.f, 0.f, 0.f);
    a1[i] = make_float4(0.f, 0.f, 0.f, 0.f);
  }

  for (int k = 0; k < D; k += 2) {
    const float4 w00 = *(const float4*)(W0 + (k + 0) * D + d4);
    const float4 w01 = *(const float4*)(W0 + (k + 1) * D + d4);
    const float4 w10 = *(const float4*)(W1 + (k + 0) * D + d4);
    const float4 w11 = *(const float4*)(W1 + (k + 1) * D + d4);
#pragma unroll
    for (int i = 0; i < 8; ++i) {
      const float x0 = xs[nloc + i][k];
      const float x1 = xs[nloc + i][k + 1];
      a0[i].x = fmaf(x0, w00.x, a0[i].x); a0[i].y = fmaf(x0, w00.y, a0[i].y);
      a0[i].z = fmaf(x0, w00.z, a0[i].z); a0[i].w = fmaf(x0, w00.w, a0[i].w);
      a0[i].x = fmaf(x1, w01.x, a0[i].x); a0[i].y = fmaf(x1, w01.y, a0[i].y);
      a0[i].z = fmaf(x1, w01.z, a0[i].z); a0[i].w = fmaf(x1, w01.w, a0[i].w);
      a1[i].x = fmaf(x0, w10.x, a1[i].x); a1[i].y = fmaf(x0, w10.y, a1[i].y);
      a1[i].z = fmaf(x0, w10.z, a1[i].z); a1[i].w = fmaf(x0, w10.w, a1[i].w);
      a1[i].x = fmaf(x1, w11.x, a1[i].x); a1[i].y = fmaf(x1, w11.y, a1[i].y);
      a1[i].z = fmaf(x1, w11.z, a1[i].z); a1[i].w = fmaf(x1, w11.w, a1[i].w);
    }
  }

#pragma unroll
  for (int i = 0; i < 8; ++i) {
    const int n = nbase + nloc + i;
    if (n < N_NODES) {
      ushort4 p0, p1;
      p0.x = f2bf(a0[i].x); p0.y = f2bf(a0[i].y);
      p0.z = f2bf(a0[i].z); p0.w = f2bf(a0[i].w);
      p1.x = f2bf(a1[i].x); p1.y = f2bf(a1[i].y);
      p1.z = f2bf(a1[i].z); p1.w = f2bf(a1[i].w);
      *(ushort4*)(preb + (size_t)n * D + d4) = p0;
      *(ushort4*)(preb + (size_t)(N_NODES + n) * D + d4) = p1;
    }
  }
}

// ============================================================================
// Bucket build: hist -> single-block scan -> chunk-local scatter
// counter index: (sup*NBKT + bucket)*8 + chunk,  chunk = blockIdx.x & 7 (~XCD)
// ============================================================================
__global__ __launch_bounds__(256) void hist_kernel(
    const int* __restrict__ rows0, const int* __restrict__ rows1,
    int* __restrict__ cnt) {
  const int e = blockIdx.x * 256 + threadIdx.x;
  if (e >= N_EDGES) return;
  const int sup = blockIdx.y;
  const int r = (sup == 0 ? rows0 : rows1)[e];
  const int idx = ((sup * NBKT + (r >> 6)) << 3) + (blockIdx.x & 7);
  atomicAdd(&cnt[idx], 1);
}

__global__ __launch_bounds__(1024) void scan_kernel(
    const int* __restrict__ cnt, int* __restrict__ basefill,
    int* __restrict__ bstart) {
  __shared__ int sums[1024];
  const int t = threadIdx.x;
  const int base_i = t * 13;
  int loc[13];
  int s = 0;
#pragma unroll
  for (int k = 0; k < 13; ++k) {
    const int g = base_i + k;
    const int v = (g < NCNT) ? cnt[g] : 0;
    loc[k] = v;
    s += v;
  }
  sums[t] = s;
  __syncthreads();
  for (int off = 1; off < 1024; off <<= 1) {
    const int v = sums[t];
    const int u = (t >= off) ? sums[t - off] : 0;
    __syncthreads();
    sums[t] = v + u;
    __syncthreads();
  }
  int excl = (t == 0) ? 0 : sums[t - 1];
#pragma unroll
  for (int k = 0; k < 13; ++k) {
    const int g = base_i + k;
    if (g < NCNT) {
      basefill[g] = excl;
      if ((g & 7) == 0) bstart[g >> 3] = excl;
      excl += loc[k];
    }
  }
  if (t == 1023) bstart[2 * NBKT] = 2 * N_EDGES;
}

// cv entry: x = col | (row%64 << 16), y = bits(val)   (col < 65536 ok)
__global__ __launch_bounds__(256) void fill_kernel(
    const int* __restrict__ rows0, const int* __restrict__ cols0,
    const float* __restrict__ vals0, const int* __restrict__ rows1,
    const int* __restrict__ cols1, const float* __restrict__ vals1,
    int* __restrict__ basefill, int2* __restrict__ cv) {
  const int e = blockIdx.x * 256 + threadIdx.x;
  if (e >= N_EDGES) return;
  const int sup = blockIdx.y;
  const int* rows = (sup == 0) ? rows0 : rows1;
  const int* cols = (sup == 0) ? cols0 : cols1;
  const float* vals = (sup == 0) ? vals0 : vals1;
  const int r = rows[e];
  const int idx = ((sup * NBKT + (r >> 6)) << 3) + (blockIdx.x & 7);
  const int p = atomicAdd(&basefill[idx], 1);
  cv[p] = make_int2(cols[e] | ((r & 63) << 16), __float_as_int(vals[e]));
}

// ============================================================================
// In-place per-bucket counting sort -> exact CSR + rs[].
// One block per (bucket, support). Whole segment staged in registers
// (cap 4096 = mean 768 + 120 sigma), so in-place rewrite is race-free.
// Reads and writes are both contiguous within the segment: no write-amp.
// ============================================================================
__global__ __launch_bounds__(256) void sort_kernel(
    const int* __restrict__ bstart, int2* __restrict__ cv,
    int* __restrict__ rs) {
  const int b = blockIdx.x;
  const int sup = blockIdx.y;
  const int s = bstart[sup * NBKT + b];
  const int e = bstart[sup * NBKT + b + 1];
  const int n = e - s;
  const int tid = threadIdx.x;

  __shared__ int cnt[64];
  __shared__ int base[64];
  __shared__ int off[64];
  if (tid < 64) cnt[tid] = 0;
  __syncthreads();

  int2 ed[16];
  int rl[16];
#pragma unroll
  for (int k = 0; k < 16; ++k) {
    const int i = tid + k * 256;
    rl[k] = -1;
    if (i < n) {
      ed[k] = cv[s + i];
      rl[k] = (ed[k].x >> 16) & 63;
      atomicAdd(&cnt[rl[k]], 1);
    }
  }
  __syncthreads();

  if (tid == 0) {
    int run = 0;
    for (int r = 0; r < 64; ++r) {
      base[r] = run;
      run += cnt[r];
      off[r] = 0;
    }
  }
  __syncthreads();

  if (tid < 64) {
    const int row = b * 64 + tid;
    if (row < N_NODES) rs[sup * (N_NODES + 1) + row] = s + base[tid];
  }
  if (b == NBKT - 1 && tid == 0) rs[sup * (N_NODES + 1) + N_NODES] = e;

#pragma unroll
  for (int k = 0; k < 16; ++k) {
    if (rl[k] >= 0) {
      const int pos = base[rl[k]] + atomicAdd(&off[rl[k]], 1);
      cv[s + pos] = ed[k];
    }
  }
}

// ============================================================================
// Fused SpMM gather: one wave per row, both supports + bias + relu.
// 4 edge-groups x 16 dim-lanes x 8 dims (bf16 uint4 gather = 16B/lane).
// ============================================================================
__global__ __launch_bounds__(256) void spmm_fused_kernel(
    const int* __restrict__ rs, const int2* __restrict__ cv,
    const unsigned short* __restrict__ preb, const float* __restrict__ bias,
    float* __restrict__ out) {
  const int row = blockIdx.x * 4 + (threadIdx.x >> 6);
  const int lane = threadIdx.x & 63;
  const int g = lane >> 4;
  const int dbase = (lane & 15) << 3;

  float acc[8];
#pragma unroll
  for (int i = 0; i < 8; ++i) acc[i] = 0.f;

#pragma unroll
  for (int sup = 0; sup < 2; ++sup) {
    const int s = rs[sup * (N_NODES + 1) + row];
    const int e = rs[sup * (N_NODES + 1) + row + 1];
    const unsigned short* pb = preb + (size_t)sup * N_NODES * D;
    for (int j = s; j < e; j += 64) {
      const int nb = min(64, e - j);
      int2 ev = make_int2(0, 0);
      if (lane < nb) ev = cv[j + lane];
      for (int t4 = 0; t4 < nb; t4 += 4) {
        const int t = t4 + g;
        const int cx = __shfl(ev.x, t & 63);
        const float vt = __int_as_float(__shfl(ev.y, t & 63));
        if (t < nb) {
          const int c = cx & 0xFFFF;
          const uint4 q = *(const uint4*)(pb + (size_t)c * D + dbase);
          const float p0 = __uint_as_float(q.x << 16);
          const float p1 = __uint_as_float(q.x & 0xFFFF0000u);
          const float p2 = __uint_as_float(q.y << 16);
          const float p3 = __uint_as_float(q.y & 0xFFFF0000u);
          const float p4 = __uint_as_float(q.z << 16);
          const float p5 = __uint_as_float(q.z & 0xFFFF0000u);
          const float p6 = __uint_as_float(q.w << 16);
          const float p7 = __uint_as_float(q.w & 0xFFFF0000u);
          acc[0] = fmaf(vt, p0, acc[0]);
          acc[1] = fmaf(vt, p1, acc[1]);
          acc[2] = fmaf(vt, p2, acc[2]);
          acc[3] = fmaf(vt, p3, acc[3]);
          acc[4] = fmaf(vt, p4, acc[4]);
          acc[5] = fmaf(vt, p5, acc[5]);
          acc[6] = fmaf(vt, p6, acc[6]);
          acc[7] = fmaf(vt, p7, acc[7]);
        }
      }
    }
  }

#pragma unroll
  for (int i = 0; i < 8; ++i) {
    acc[i] += __shfl_xor(acc[i], 16);
    acc[i] += __shfl_xor(acc[i], 32);
  }

  if (g == 0) {
    const float4 b0 = *(const float4*)(bias + dbase);
    const float4 b1 = *(const float4*)(bias + dbase + 4);
    float4 r0, r1;
    r0.x = fmaxf(acc[0] + b0.x, 0.f);
    r0.y = fmaxf(acc[1] + b0.y, 0.f);
    r0.z = fmaxf(acc[2] + b0.z, 0.f);
    r0.w = fmaxf(acc[3] + b0.w, 0.f);
    r1.x = fmaxf(acc[4] + b1.x, 0.f);
    r1.y = fmaxf(acc[5] + b1.y, 0.f);
    r1.z = fmaxf(acc[6] + b1.z, 0.f);
    r1.w = fmaxf(acc[7] + b1.w, 0.f);
    float* op = out + (size_t)row * D + dbase;
    *(float4*)op = r0;
    *(float4*)(op + 4) = r1;
  }
}

// ============================================================================
// Fallback: fp32 gemm + atomic scatter (used only if workspace too small)
// ============================================================================
__global__ __launch_bounds__(256) void gemm_f32_kernel(
    const float* __restrict__ x, const float* __restrict__ W,
    float* __restrict__ pre) {
  const int tid = threadIdx.x;
  const int nloc = (tid >> 5) << 3;
  const int d4 = (tid & 31) << 2;
  const int nbase = blockIdx.x * 64;
  __shared__ float xs[64][D];
  {
    float4* xs4 = (float4*)(&xs[0][0]);
    const float4* xg4 = (const float4*)x;
#pragma unroll
    for (int i = 0; i < 8; ++i) {
      const int idx = tid + i * 256;
      const int row = nbase + (idx >> 5);
      xs4[idx] = (row < N_NODES) ? xg4[(size_t)row * 32 + (idx & 31)]
                                 : make_float4(0.f, 0.f, 0.f, 0.f);
    }
  }
  __syncthreads();
  float4 acc[8];
#pragma unroll
  for (int i = 0; i < 8; ++i) acc[i] = make_float4(0.f, 0.f, 0.f, 0.f);
  for (int k = 0; k < D; ++k) {
    const float4 w = *(const float4*)(W + k * D + d4);
#pragma unroll
    for (int i = 0; i < 8; ++i) {
      const float xv = xs[nloc + i][k];
      acc[i].x = fmaf(xv, w.x, acc[i].x);
      acc[i].y = fmaf(xv, w.y, acc[i].y);
      acc[i].z = fmaf(xv, w.z, acc[i].z);
      acc[i].w = fmaf(xv, w.w, acc[i].w);
    }
  }
#pragma unroll
  for (int i = 0; i < 8; ++i) {
    const int n = nbase + nloc + i;
    if (n < N_NODES) *(float4*)(pre + (size_t)n * D + d4) = acc[i];
  }
}

__global__ __launch_bounds__(256) void spmm_scatter_kernel(
    const int* __restrict__ rows, const int* __restrict__ cols,
    const float* __restrict__ vals, const float* __restrict__ pre,
    float* __restrict__ out) {
  const long long idx = (long long)blockIdx.x * blockDim.x + threadIdx.x;
  const int e = (int)(idx >> 6);
  if (e >= N_EDGES) return;
  const int dd = ((int)idx & 63) << 1;
  const int r = rows[e];
  const int c = cols[e];
  const float v = vals[e];
  const float2 p = *(const float2*)(pre + (size_t)c * D + dd);
  float* outp = out + (size_t)r * D + dd;
  atomicAdd(outp + 0, v * p.x);
  atomicAdd(outp + 1, v * p.y);
}

__global__ __launch_bounds__(256) void bias_relu_kernel(
    float* __restrict__ out, const float* __restrict__ b) {
  const int idx = blockIdx.x * blockDim.x + threadIdx.x;
  float4 v = ((float4*)out)[idx];
  const float4 bb = ((const float4*)b)[idx & 31];
  v.x = fmaxf(v.x + bb.x, 0.f);
  v.y = fmaxf(v.y + bb.y, 0.f);
  v.z = fmaxf(v.z + bb.z, 0.f);
  v.w = fmaxf(v.w + bb.w, 0.f);
  ((float4*)out)[idx] = v;
}

extern "C" void kernel_launch(void* const* d_in, const int* in_sizes, int n_in,
                              void* d_out, int out_size, void* d_ws,
                              size_t ws_size, hipStream_t stream) {
  const float* x = (const float*)d_in[0];
  const float* W0 = (const float*)d_in[1];
  const float* W1 = (const float*)d_in[2];
  const float* b = (const float*)d_in[3];
  const int* rows0 = (const int*)d_in[4];
  const int* cols0 = (const int*)d_in[5];
  const float* vals0 = (const float*)d_in[6];
  const int* rows1 = (const int*)d_in[7];
  const int* cols1 = (const int*)d_in[8];
  const float* vals1 = (const float*)d_in[9];
  float* out = (float*)d_out;

  auto align_up = [](size_t v) { return (v + 255) & ~(size_t)255; };
  const size_t PREB = align_up((size_t)2 * N_NODES * D * 2);  // 25.6 MB bf16
  const size_t CV = align_up((size_t)2 * N_EDGES * 8);        // 9.6 MB
  const size_t CNT = align_up((size_t)NCNT * 4);
  const size_t BFILL = align_up((size_t)NCNT * 4);
  const size_t BSTART = align_up((size_t)NBSTART * 4);
  const size_t RS = align_up((size_t)2 * (N_NODES + 1) * 4);  // 400 KB
  const size_t NEED = PREB + CV + CNT + BFILL + BSTART + RS;

  char* wsc = (char*)d_ws;

  if (ws_size >= NEED) {
    unsigned short* preb = (unsigned short*)wsc;
    int2* cv = (int2*)(wsc + PREB);
    int* cnt = (int*)(wsc + PREB + CV);
    int* basefill = (int*)(wsc + PREB + CV + CNT);
    int* bstart = (int*)(wsc + PREB + CV + CNT + BFILL);
    int* rs = (int*)(wsc + PREB + CV + CNT + BFILL + BSTART);

    hipMemsetAsync(cnt, 0, (size_t)NCNT * 4, stream);
    hist_kernel<<<dim3(EDGE_BLOCKS, 2), 256, 0, stream>>>(rows0, rows1, cnt);
    scan_kernel<<<1, 1024, 0, stream>>>(cnt, basefill, bstart);
    fill_kernel<<<dim3(EDGE_BLOCKS, 2), 256, 0, stream>>>(
        rows0, cols0, vals0, rows1, cols1, vals1, basefill, cv);
    sort_kernel<<<dim3(NBKT, 2), 256, 0, stream>>>(bstart, cv, rs);
    gemm2_kernel<<<NBKT, 256, 0, stream>>>(x, W0, W1, preb);
    spmm_fused_kernel<<<N_NODES / 4, 256, 0, stream>>>(rs, cv, preb, b, out);
  } else {
    float* pre = (float*)wsc;
    hipMemsetAsync(d_out, 0, (size_t)N_NODES * D * 4, stream);
    const int scat_blocks = (N_EDGES * 64 + 255) / 256;
    gemm_f32_kernel<<<NBKT, 256, 0, stream>>>(x, W0, pre);
    spmm_scatter_kernel<<<scat_blocks, 256, 0, stream>>>(rows0, cols0, vals0,
                                                         pre, out);
    gemm_f32_kernel<<<NBKT, 256, 0, stream>>>(x, W1, pre);
    spmm_scatter_kernel<<<scat_blocks, 256, 0, stream>>>(rows1, cols1, vals1,
                                                         pre, out);
    bias_relu_kernel<<<(N_NODES * D / 4) / 256, 256, 0, stream>>>(out, b);
  }
}

// Round 6
// 219.333 us; speedup vs baseline: 5.6873x; 1.2523x over previous
//
#include <hip/hip_runtime.h>

#define N_NODES 50000
#define N_EDGES 600000
#define D 128
#define NBKT 782            // ceil(50000/64) buckets of 64 rows
#define NCNT (2 * NBKT * 8) // 12512 counters (2 supports x 8 chunks)
#define NBSTART (2 * NBKT + 1)
#define EDGE_BLOCKS 2344    // ceil(600000/256)

typedef __attribute__((ext_vector_type(8))) short short8v;  // 8 bf16
typedef __attribute__((ext_vector_type(4))) float f32x4;

__device__ __forceinline__ unsigned short f2bf(float f) {
  unsigned u = __float_as_uint(f);
  return (unsigned short)((u + 0x7FFFu + ((u >> 16) & 1u)) >> 16);
}

// ============================================================================
// W prepack: Wpack[sup][ct(8)][ks(4)][lane(64)][i(8)] = bf16(W[k][d])
//   k = ks*32 + (lane>>4)*8 + i,  d = ct*16 + (lane&15)
// One B-frag load in the GEMM = 16B contiguous per lane.
// ============================================================================
__global__ __launch_bounds__(256) void wpack_kernel(
    const float* __restrict__ W0, const float* __restrict__ W1,
    unsigned short* __restrict__ wpack) {
  const int idx = blockIdx.x * 256 + threadIdx.x;  // 0..4095
  const int sup = idx >> 11;
  const int ct = (idx >> 8) & 7;
  const int ks = (idx >> 6) & 3;
  const int l = idx & 63;
  const int q = l >> 4;
  const int c = l & 15;
  const float* W = (sup == 0) ? W0 : W1;
  const int d = ct * 16 + c;
  unsigned short v[8];
#pragma unroll
  for (int i = 0; i < 8; ++i) {
    const int k = ks * 32 + q * 8 + i;
    v[i] = f2bf(W[k * D + d]);
  }
  *(uint4*)(wpack + (size_t)idx * 8) = *(uint4*)v;
}

// ============================================================================
// MFMA GEMM: preb[sup][n][d] = bf16( sum_k x[n][k] * W{sup}[k][d] )
// Block: 64 rows, 4 waves (16 rows each). A-frags loaded once from global
// (fp32 -> bf16 pack), B-frags 16B/lane from wpack (L2-resident).
// ============================================================================
__global__ __launch_bounds__(256) void gemm_mfma_kernel(
    const float* __restrict__ x, const unsigned short* __restrict__ wpack,
    unsigned short* __restrict__ preb) {
  const int w = threadIdx.x >> 6;
  const int lane = threadIdx.x & 63;
  const int q = lane >> 4;
  const int rowbase = blockIdx.x * 64 + w * 16;
  const int arow = rowbase + (lane & 15);

  short8v afrag[4];
#pragma unroll
  for (int ks = 0; ks < 4; ++ks) {
    const int k0 = ks * 32 + q * 8;
    float4 u0 = make_float4(0.f, 0.f, 0.f, 0.f);
    float4 u1 = u0;
    if (arow < N_NODES) {
      u0 = *(const float4*)(x + (size_t)arow * D + k0);
      u1 = *(const float4*)(x + (size_t)arow * D + k0 + 4);
    }
    unsigned short a[8];
    a[0] = f2bf(u0.x); a[1] = f2bf(u0.y); a[2] = f2bf(u0.z); a[3] = f2bf(u0.w);
    a[4] = f2bf(u1.x); a[5] = f2bf(u1.y); a[6] = f2bf(u1.z); a[7] = f2bf(u1.w);
    afrag[ks] = *(const short8v*)a;
  }

  const short8v* wp = (const short8v*)wpack;
#pragma unroll
  for (int sup = 0; sup < 2; ++sup) {
    unsigned short* pb = preb + (size_t)sup * N_NODES * D;
#pragma unroll
    for (int ct = 0; ct < 8; ++ct) {
      f32x4 acc = {0.f, 0.f, 0.f, 0.f};
#pragma unroll
      for (int ks = 0; ks < 4; ++ks) {
        const short8v bfrag = wp[((sup * 8 + ct) * 4 + ks) * 64 + lane];
        acc = __builtin_amdgcn_mfma_f32_16x16x32_bf16(afrag[ks], bfrag, acc,
                                                      0, 0, 0);
      }
      const int dcol = ct * 16 + (lane & 15);
#pragma unroll
      for (int j = 0; j < 4; ++j) {
        const int r = rowbase + q * 4 + j;
        if (r < N_NODES) pb[(size_t)r * D + dcol] = f2bf(acc[j]);
      }
    }
  }
}

// ============================================================================
// Bucket build: hist -> single-block scan -> chunk-local scatter
// counter index: (sup*NBKT + bucket)*8 + chunk,  chunk = blockIdx.x & 7 (~XCD)
// ============================================================================
__global__ __launch_bounds__(256) void hist_kernel(
    const int* __restrict__ rows0, const int* __restrict__ rows1,
    int* __restrict__ cnt) {
  const int e = blockIdx.x * 256 + threadIdx.x;
  if (e >= N_EDGES) return;
  const int sup = blockIdx.y;
  const int r = (sup == 0 ? rows0 : rows1)[e];
  const int idx = ((sup * NBKT + (r >> 6)) << 3) + (blockIdx.x & 7);
  atomicAdd(&cnt[idx], 1);
}

__global__ __launch_bounds__(1024) void scan_kernel(
    const int* __restrict__ cnt, int* __restrict__ basefill,
    int* __restrict__ bstart) {
  __shared__ int sums[1024];
  const int t = threadIdx.x;
  const int base_i = t * 13;
  int loc[13];
  int s = 0;
#pragma unroll
  for (int k = 0; k < 13; ++k) {
    const int g = base_i + k;
    const int v = (g < NCNT) ? cnt[g] : 0;
    loc[k] = v;
    s += v;
  }
  sums[t] = s;
  __syncthreads();
  for (int off = 1; off < 1024; off <<= 1) {
    const int v = sums[t];
    const int u = (t >= off) ? sums[t - off] : 0;
    __syncthreads();
    sums[t] = v + u;
    __syncthreads();
  }
  int excl = (t == 0) ? 0 : sums[t - 1];
#pragma unroll
  for (int k = 0; k < 13; ++k) {
    const int g = base_i + k;
    if (g < NCNT) {
      basefill[g] = excl;
      if ((g & 7) == 0) bstart[g >> 3] = excl;
      excl += loc[k];
    }
  }
  if (t == 1023) bstart[2 * NBKT] = 2 * N_EDGES;
}

// cv entry: x = col | (row%64 << 16), y = bits(val)   (col < 65536 ok)
__global__ __launch_bounds__(256) void fill_kernel(
    const int* __restrict__ rows0, const int* __restrict__ cols0,
    const float* __restrict__ vals0, const int* __restrict__ rows1,
    const int* __restrict__ cols1, const float* __restrict__ vals1,
    int* __restrict__ basefill, int2* __restrict__ cv) {
  const int e = blockIdx.x * 256 + threadIdx.x;
  if (e >= N_EDGES) return;
  const int sup = blockIdx.y;
  const int* rows = (sup == 0) ? rows0 : rows1;
  const int* cols = (sup == 0) ? cols0 : cols1;
  const float* vals = (sup == 0) ? vals0 : vals1;
  const int r = rows[e];
  const int idx = ((sup * NBKT + (r >> 6)) << 3) + (blockIdx.x & 7);
  const int p = atomicAdd(&basefill[idx], 1);
  cv[p] = make_int2(cols[e] | ((r & 63) << 16), __float_as_int(vals[e]));
}

// ============================================================================
// In-place per-bucket counting sort -> exact CSR + rs[].
// ============================================================================
__global__ __launch_bounds__(256) void sort_kernel(
    const int* __restrict__ bstart, int2* __restrict__ cv,
    int* __restrict__ rs) {
  const int b = blockIdx.x;
  const int sup = blockIdx.y;
  const int s = bstart[sup * NBKT + b];
  const int e = bstart[sup * NBKT + b + 1];
  const int n = e - s;
  const int tid = threadIdx.x;

  __shared__ int cnt[64];
  __shared__ int base[64];
  __shared__ int off[64];
  if (tid < 64) cnt[tid] = 0;
  __syncthreads();

  int2 ed[16];
  int rl[16];
#pragma unroll
  for (int k = 0; k < 16; ++k) {
    const int i = tid + k * 256;
    rl[k] = -1;
    if (i < n) {
      ed[k] = cv[s + i];
      rl[k] = (ed[k].x >> 16) & 63;
      atomicAdd(&cnt[rl[k]], 1);
    }
  }
  __syncthreads();

  if (tid == 0) {
    int run = 0;
    for (int r = 0; r < 64; ++r) {
      base[r] = run;
      run += cnt[r];
      off[r] = 0;
    }
  }
  __syncthreads();

  if (tid < 64) {
    const int row = b * 64 + tid;
    if (row < N_NODES) rs[sup * (N_NODES + 1) + row] = s + base[tid];
  }
  if (b == NBKT - 1 && tid == 0) rs[sup * (N_NODES + 1) + N_NODES] = e;

#pragma unroll
  for (int k = 0; k < 16; ++k) {
    if (rl[k] >= 0) {
      const int pos = base[rl[k]] + atomicAdd(&off[rl[k]], 1);
      cv[s + pos] = ed[k];
    }
  }
}

// ============================================================================
// Fused SpMM gather: one wave per row, both supports + bias + relu.
// 4 edge-groups x 16 dim-lanes x 8 dims (bf16 uint4 gather = 16B/lane).
// ============================================================================
__global__ __launch_bounds__(256) void spmm_fused_kernel(
    const int* __restrict__ rs, const int2* __restrict__ cv,
    const unsigned short* __restrict__ preb, const float* __restrict__ bias,
    float* __restrict__ out) {
  const int row = blockIdx.x * 4 + (threadIdx.x >> 6);
  const int lane = threadIdx.x & 63;
  const int g = lane >> 4;
  const int dbase = (lane & 15) << 3;

  float acc[8];
#pragma unroll
  for (int i = 0; i < 8; ++i) acc[i] = 0.f;

#pragma unroll
  for (int sup = 0; sup < 2; ++sup) {
    const int s = rs[sup * (N_NODES + 1) + row];
    const int e = rs[sup * (N_NODES + 1) + row + 1];
    const unsigned short* pb = preb + (size_t)sup * N_NODES * D;
    for (int j = s; j < e; j += 64) {
      const int nb = min(64, e - j);
      int2 ev = make_int2(0, 0);
      if (lane < nb) ev = cv[j + lane];
      for (int t4 = 0; t4 < nb; t4 += 4) {
        const int t = t4 + g;
        const int cx = __shfl(ev.x, t & 63);
        const float vt = __int_as_float(__shfl(ev.y, t & 63));
        if (t < nb) {
          const int c = cx & 0xFFFF;
          const uint4 qv = *(const uint4*)(pb + (size_t)c * D + dbase);
          const float p0 = __uint_as_float(qv.x << 16);
          const float p1 = __uint_as_float(qv.x & 0xFFFF0000u);
          const float p2 = __uint_as_float(qv.y << 16);
          const float p3 = __uint_as_float(qv.y & 0xFFFF0000u);
          const float p4 = __uint_as_float(qv.z << 16);
          const float p5 = __uint_as_float(qv.z & 0xFFFF0000u);
          const float p6 = __uint_as_float(qv.w << 16);
          const float p7 = __uint_as_float(qv.w & 0xFFFF0000u);
          acc[0] = fmaf(vt, p0, acc[0]);
          acc[1] = fmaf(vt, p1, acc[1]);
          acc[2] = fmaf(vt, p2, acc[2]);
          acc[3] = fmaf(vt, p3, acc[3]);
          acc[4] = fmaf(vt, p4, acc[4]);
          acc[5] = fmaf(vt, p5, acc[5]);
          acc[6] = fmaf(vt, p6, acc[6]);
          acc[7] = fmaf(vt, p7, acc[7]);
        }
      }
    }
  }

#pragma unroll
  for (int i = 0; i < 8; ++i) {
    acc[i] += __shfl_xor(acc[i], 16);
    acc[i] += __shfl_xor(acc[i], 32);
  }

  if (g == 0) {
    const float4 b0 = *(const float4*)(bias + dbase);
    const float4 b1 = *(const float4*)(bias + dbase + 4);
    float4 r0, r1;
    r0.x = fmaxf(acc[0] + b0.x, 0.f);
    r0.y = fmaxf(acc[1] + b0.y, 0.f);
    r0.z = fmaxf(acc[2] + b0.z, 0.f);
    r0.w = fmaxf(acc[3] + b0.w, 0.f);
    r1.x = fmaxf(acc[4] + b1.x, 0.f);
    r1.y = fmaxf(acc[5] + b1.y, 0.f);
    r1.z = fmaxf(acc[6] + b1.z, 0.f);
    r1.w = fmaxf(acc[7] + b1.w, 0.f);
    float* op = out + (size_t)row * D + dbase;
    *(float4*)op = r0;
    *(float4*)(op + 4) = r1;
  }
}

// ============================================================================
// Fallback: fp32 gemm + atomic scatter (used only if workspace too small)
// ============================================================================
__global__ __launch_bounds__(256) void gemm_f32_kernel(
    const float* __restrict__ x, const float* __restrict__ W,
    float* __restrict__ pre) {
  const int tid = threadIdx.x;
  const int nloc = (tid >> 5) << 3;
  const int d4 = (tid & 31) << 2;
  const int nbase = blockIdx.x * 64;
  __shared__ float xs[64][D];
  {
    float4* xs4 = (float4*)(&xs[0][0]);
    const float4* xg4 = (const float4*)x;
#pragma unroll
    for (int i = 0; i < 8; ++i) {
      const int idx = tid + i * 256;
      const int row = nbase + (idx >> 5);
      xs4[idx] = (row < N_NODES) ? xg4[(size_t)row * 32 + (idx & 31)]
                                 : make_float4(0.f, 0.f, 0.f, 0.f);
    }
  }
  __syncthreads();
  float4 acc[8];
#pragma unroll
  for (int i = 0; i < 8; ++i) acc[i] = make_float4(0.f, 0.f, 0.f, 0.f);
  for (int k = 0; k < D; ++k) {
    const float4 w = *(const float4*)(W + k * D + d4);
#pragma unroll
    for (int i = 0; i < 8; ++i) {
      const float xv = xs[nloc + i][k];
      acc[i].x = fmaf(xv, w.x, acc[i].x);
      acc[i].y = fmaf(xv, w.y, acc[i].y);
      acc[i].z = fmaf(xv, w.z, acc[i].z);
      acc[i].w = fmaf(xv, w.w, acc[i].w);
    }
  }
#pragma unroll
  for (int i = 0; i < 8; ++i) {
    const int n = nbase + nloc + i;
    if (n < N_NODES) *(float4*)(pre + (size_t)n * D + d4) = acc[i];
  }
}

__global__ __launch_bounds__(256) void spmm_scatter_kernel(
    const int* __restrict__ rows, const int* __restrict__ cols,
    const float* __restrict__ vals, const float* __restrict__ pre,
    float* __restrict__ out) {
  const long long idx = (long long)blockIdx.x * blockDim.x + threadIdx.x;
  const int e = (int)(idx >> 6);
  if (e >= N_EDGES) return;
  const int dd = ((int)idx & 63) << 1;
  const int r = rows[e];
  const int c = cols[e];
  const float v = vals[e];
  const float2 p = *(const float2*)(pre + (size_t)c * D + dd);
  float* outp = out + (size_t)r * D + dd;
  atomicAdd(outp + 0, v * p.x);
  atomicAdd(outp + 1, v * p.y);
}

__global__ __launch_bounds__(256) void bias_relu_kernel(
    float* __restrict__ out, const float* __restrict__ b) {
  const int idx = blockIdx.x * blockDim.x + threadIdx.x;
  float4 v = ((float4*)out)[idx];
  const float4 bb = ((const float4*)b)[idx & 31];
  v.x = fmaxf(v.x + bb.x, 0.f);
  v.y = fmaxf(v.y + bb.y, 0.f);
  v.z = fmaxf(v.z + bb.z, 0.f);
  v.w = fmaxf(v.w + bb.w, 0.f);
  ((float4*)out)[idx] = v;
}

extern "C" void kernel_launch(void* const* d_in, const int* in_sizes, int n_in,
                              void* d_out, int out_size, void* d_ws,
                              size_t ws_size, hipStream_t stream) {
  const float* x = (const float*)d_in[0];
  const float* W0 = (const float*)d_in[1];
  const float* W1 = (const float*)d_in[2];
  const float* b = (const float*)d_in[3];
  const int* rows0 = (const int*)d_in[4];
  const int* cols0 = (const int*)d_in[5];
  const float* vals0 = (const float*)d_in[6];
  const int* rows1 = (const int*)d_in[7];
  const int* cols1 = (const int*)d_in[8];
  const float* vals1 = (const float*)d_in[9];
  float* out = (float*)d_out;

  auto align_up = [](size_t v) { return (v + 255) & ~(size_t)255; };
  const size_t PREB = align_up((size_t)2 * N_NODES * D * 2);  // 25.6 MB bf16
  const size_t CV = align_up((size_t)2 * N_EDGES * 8);        // 9.6 MB
  const size_t CNT = align_up((size_t)NCNT * 4);
  const size_t BFILL = align_up((size_t)NCNT * 4);
  const size_t BSTART = align_up((size_t)NBSTART * 4);
  const size_t RS = align_up((size_t)2 * (N_NODES + 1) * 4);  // 400 KB
  const size_t WPACK = align_up((size_t)2 * D * D * 2);       // 64 KB
  const size_t NEED = PREB + CV + CNT + BFILL + BSTART + RS + WPACK;

  char* wsc = (char*)d_ws;

  if (ws_size >= NEED) {
    unsigned short* preb = (unsigned short*)wsc;
    int2* cv = (int2*)(wsc + PREB);
    int* cnt = (int*)(wsc + PREB + CV);
    int* basefill = (int*)(wsc + PREB + CV + CNT);
    int* bstart = (int*)(wsc + PREB + CV + CNT + BFILL);
    int* rs = (int*)(wsc + PREB + CV + CNT + BFILL + BSTART);
    unsigned short* wpack =
        (unsigned short*)(wsc + PREB + CV + CNT + BFILL + BSTART + RS);

    hipMemsetAsync(cnt, 0, (size_t)NCNT * 4, stream);
    wpack_kernel<<<16, 256, 0, stream>>>(W0, W1, wpack);
    hist_kernel<<<dim3(EDGE_BLOCKS, 2), 256, 0, stream>>>(rows0, rows1, cnt);
    scan_kernel<<<1, 1024, 0, stream>>>(cnt, basefill, bstart);
    fill_kernel<<<dim3(EDGE_BLOCKS, 2), 256, 0, stream>>>(
        rows0, cols0, vals0, rows1, cols1, vals1, basefill, cv);
    sort_kernel<<<dim3(NBKT, 2), 256, 0, stream>>>(bstart, cv, rs);
    gemm_mfma_kernel<<<NBKT, 256, 0, stream>>>(x, wpack, preb);
    spmm_fused_kernel<<<N_NODES / 4, 256, 0, stream>>>(rs, cv, preb, b, out);
  } else {
    float* pre = (float*)wsc;
    hipMemsetAsync(d_out, 0, (size_t)N_NODES * D * 4, stream);
    const int scat_blocks = (N_EDGES * 64 + 255) / 256;
    gemm_f32_kernel<<<NBKT, 256, 0, stream>>>(x, W0, pre);
    spmm_scatter_kernel<<<scat_blocks, 256, 0, stream>>>(rows0, cols0, vals0,
                                                         pre, out);
    gemm_f32_kernel<<<NBKT, 256, 0, stream>>>(x, W1, pre);
    spmm_scatter_kernel<<<scat_blocks, 256, 0, stream>>>(rows1, cols1, vals1,
                                                         pre, out);
    bias_relu_kernel<<<(N_NODES * D / 4) / 256, 256, 0, stream>>>(out, b);
  }
}

// Round 7
// 118.739 us; speedup vs baseline: 10.5055x; 1.8472x over previous
//
#include <hip/hip_runtime.h>

#define N_NODES 50000
#define N_EDGES 600000
#define D 128
#define SB 98              // super-buckets of 512 rows (ceil(50000/512))
#define NSEG (2 * SB)      // per-support segments
#define HISTBLK 2048
#define BINBLK 4096
#define HIST_BLOCKS ((N_EDGES + HISTBLK - 1) / HISTBLK)  // 293
#define BIN_BLOCKS ((N_EDGES + BINBLK - 1) / BINBLK)     // 147

typedef __attribute__((ext_vector_type(8))) short short8v;  // 8 bf16
typedef __attribute__((ext_vector_type(4))) float f32x4;

__device__ __forceinline__ unsigned short f2bf(float f) {
  unsigned u = __float_as_uint(f);
  return (unsigned short)((u + 0x7FFFu + ((u >> 16) & 1u)) >> 16);
}

// ============================================================================
// W prepack: Wpack[sup][ct(8)][ks(4)][lane(64)][i(8)] = bf16(W[k][d])
//   k = ks*32 + (lane>>4)*8 + i,  d = ct*16 + (lane&15)
// ============================================================================
__global__ __launch_bounds__(256) void wpack_kernel(
    const float* __restrict__ W0, const float* __restrict__ W1,
    unsigned short* __restrict__ wpack) {
  const int idx = blockIdx.x * 256 + threadIdx.x;  // 0..4095
  const int sup = idx >> 11;
  const int ct = (idx >> 8) & 7;
  const int ks = (idx >> 6) & 3;
  const int l = idx & 63;
  const int q = l >> 4;
  const int c = l & 15;
  const float* W = (sup == 0) ? W0 : W1;
  const int d = ct * 16 + c;
  unsigned short v[8];
#pragma unroll
  for (int i = 0; i < 8; ++i) {
    const int k = ks * 32 + q * 8 + i;
    v[i] = f2bf(W[k * D + d]);
  }
  *(uint4*)(wpack + (size_t)idx * 8) = *(uint4*)v;
}

// ============================================================================
// MFMA GEMM: preb[sup][n][d] = bf16( sum_k x[n][k] * W{sup}[k][d] )
// ============================================================================
__global__ __launch_bounds__(256) void gemm_mfma_kernel(
    const float* __restrict__ x, const unsigned short* __restrict__ wpack,
    unsigned short* __restrict__ preb) {
  const int w = threadIdx.x >> 6;
  const int lane = threadIdx.x & 63;
  const int q = lane >> 4;
  const int rowbase = blockIdx.x * 64 + w * 16;
  const int arow = rowbase + (lane & 15);

  short8v afrag[4];
#pragma unroll
  for (int ks = 0; ks < 4; ++ks) {
    const int k0 = ks * 32 + q * 8;
    float4 u0 = make_float4(0.f, 0.f, 0.f, 0.f);
    float4 u1 = u0;
    if (arow < N_NODES) {
      u0 = *(const float4*)(x + (size_t)arow * D + k0);
      u1 = *(const float4*)(x + (size_t)arow * D + k0 + 4);
    }
    unsigned short a[8];
    a[0] = f2bf(u0.x); a[1] = f2bf(u0.y); a[2] = f2bf(u0.z); a[3] = f2bf(u0.w);
    a[4] = f2bf(u1.x); a[5] = f2bf(u1.y); a[6] = f2bf(u1.z); a[7] = f2bf(u1.w);
    afrag[ks] = *(const short8v*)a;
  }

  const short8v* wp = (const short8v*)wpack;
#pragma unroll
  for (int sup = 0; sup < 2; ++sup) {
    unsigned short* pb = preb + (size_t)sup * N_NODES * D;
#pragma unroll
    for (int ct = 0; ct < 8; ++ct) {
      f32x4 acc = {0.f, 0.f, 0.f, 0.f};
#pragma unroll
      for (int ks = 0; ks < 4; ++ks) {
        const short8v bfrag = wp[((sup * 8 + ct) * 4 + ks) * 64 + lane];
        acc = __builtin_amdgcn_mfma_f32_16x16x32_bf16(afrag[ks], bfrag, acc,
                                                      0, 0, 0);
      }
      const int dcol = ct * 16 + (lane & 15);
#pragma unroll
      for (int j = 0; j < 4; ++j) {
        const int r = rowbase + q * 4 + j;
        if (r < N_NODES) pb[(size_t)r * D + dcol] = f2bf(acc[j]);
      }
    }
  }
}

// ============================================================================
// Stage 1: exact super-bucket histogram (LDS-aggregated)
// ============================================================================
__global__ __launch_bounds__(256) void hist_kernel(
    const int* __restrict__ rows0, const int* __restrict__ rows1,
    int* __restrict__ cnt) {
  __shared__ int h[SB];
  const int t = threadIdx.x;
  if (t < SB) h[t] = 0;
  __syncthreads();
  const int sup = blockIdx.y;
  const int* rows = sup ? rows1 : rows0;
  int e = blockIdx.x * HISTBLK + t;
#pragma unroll
  for (int k = 0; k < HISTBLK / 256; ++k, e += 256)
    if (e < N_EDGES) atomicAdd(&h[rows[e] >> 9], 1);
  __syncthreads();
  if (t < SB && h[t] > 0) atomicAdd(&cnt[sup * SB + t], h[t]);
}

// ============================================================================
// Stage 2: exclusive scan of the 196 segment counts (one block)
// ============================================================================
__global__ __launch_bounds__(256) void scan196_kernel(
    const int* __restrict__ cnt, int* __restrict__ fillc,
    int* __restrict__ sbstart) {
  __shared__ int sh[256];
  const int t = threadIdx.x;
  const int v = (t < NSEG) ? cnt[t] : 0;
  sh[t] = v;
  __syncthreads();
  for (int off = 1; off < 256; off <<= 1) {
    const int u = (t >= off) ? sh[t - off] : 0;
    __syncthreads();
    sh[t] += u;
    __syncthreads();
  }
  if (t < NSEG) {
    const int ex = sh[t] - v;
    fillc[t] = ex;
    sbstart[t] = ex;
  }
  if (t == 0) sbstart[NSEG] = 2 * N_EDGES;
}

// ============================================================================
// Stage 3: line-dense binning. Block sorts 4096 edges by super-bucket in
// LDS, bump-allocates one contiguous global run per bucket, then copies runs
// out with consecutive lanes -> consecutive addresses (full-line writes).
// cv.x = col(16) | rloc(9)<<16 | sb(7)<<25 ; cv.y = bits(val)
// ============================================================================
__global__ __launch_bounds__(256) void bin_kernel(
    const int* __restrict__ rows0, const int* __restrict__ cols0,
    const float* __restrict__ vals0, const int* __restrict__ rows1,
    const int* __restrict__ cols1, const float* __restrict__ vals1,
    int* __restrict__ fillc, int2* __restrict__ cv) {
  __shared__ int hist[SB];
  __shared__ int lsum[SB];   // inclusive scan
  __shared__ int lpos[SB];   // bump counters
  __shared__ int gbase[SB];  // global run bases
  __shared__ int2 stage[BINBLK];  // 32 KB

  const int t = threadIdx.x;
  const int sup = blockIdx.y;
  const int* rows = sup ? rows1 : rows0;
  const int* cols = sup ? cols1 : cols0;
  const float* vals = sup ? vals1 : vals0;
  const int ebase = blockIdx.x * BINBLK;
  const int nloc = min(BINBLK, N_EDGES - ebase);

  if (t < SB) hist[t] = 0;
  __syncthreads();

  int myr[16], myc[16];
  float myv[16];
#pragma unroll
  for (int k = 0; k < 16; ++k) {
    const int i = t + k * 256;
    myr[k] = -1;
    if (i < nloc) {
      myr[k] = rows[ebase + i];
      myc[k] = cols[ebase + i];
      myv[k] = vals[ebase + i];
      atomicAdd(&hist[myr[k] >> 9], 1);
    }
  }
  __syncthreads();

  if (t < SB) lsum[t] = hist[t];
  __syncthreads();
  for (int off = 1; off < SB; off <<= 1) {
    int u = 0;
    if (t < SB && t >= off) u = lsum[t - off];
    __syncthreads();
    if (t < SB) lsum[t] += u;
    __syncthreads();
  }
  if (t < SB) lpos[t] = lsum[t] - hist[t];  // exclusive start
  __syncthreads();

#pragma unroll
  for (int k = 0; k < 16; ++k) {
    if (myr[k] >= 0) {
      const int sb = myr[k] >> 9;
      const int p = atomicAdd(&lpos[sb], 1);
      stage[p] = make_int2(myc[k] | ((myr[k] & 511) << 16) | (sb << 25),
                           __float_as_int(myv[k]));
    }
  }
  if (t < SB && hist[t] > 0)
    gbase[t] = atomicAdd(&fillc[sup * SB + t], hist[t]);
  __syncthreads();

  for (int i = t; i < nloc; i += 256) {
    const int2 ev = stage[i];
    const int sb = ((unsigned)ev.x) >> 25;
    cv[gbase[sb] + (i - (lsum[sb] - hist[sb]))] = ev;
  }
}

// ============================================================================
// Stage 4: per-super-bucket counting sort by row -> row-sorted cv + rs[].
// One block per (sb, support), 1024 threads, segment staged in registers.
// ============================================================================
__global__ __launch_bounds__(1024) void sort_kernel(
    const int* __restrict__ sbstart, int2* __restrict__ cv,
    int* __restrict__ rs) {
  const int sb = blockIdx.x;
  const int sup = blockIdx.y;
  const int s = sbstart[sup * SB + sb];
  const int e = sbstart[sup * SB + sb + 1];
  const int n = e - s;
  const int t = threadIdx.x;

  __shared__ int cnt[512];
  __shared__ int base[512];
  __shared__ int off[512];
  if (t < 512) {
    cnt[t] = 0;
    off[t] = 0;
  }
  __syncthreads();

  int2 ed[8];
#pragma unroll
  for (int k = 0; k < 8; ++k) {
    const int i = t + k * 1024;
    if (i < n) {
      ed[k] = cv[s + i];
      atomicAdd(&cnt[(ed[k].x >> 16) & 511], 1);
    }
  }
  __syncthreads();

  if (t < 512) base[t] = cnt[t];
  __syncthreads();
  for (int o = 1; o < 512; o <<= 1) {
    int u = 0;
    if (t < 512 && t >= o) u = base[t - o];
    __syncthreads();
    if (t < 512) base[t] += u;
    __syncthreads();
  }
  // base = inclusive; write rs with exclusive, then convert base to exclusive
  if (t < 512) {
    const int row = sb * 512 + t;
    if (row < N_NODES) rs[sup * (N_NODES + 1) + row] = s + base[t] - cnt[t];
    base[t] -= cnt[t];
  }
  if (sb == SB - 1 && t == 0) rs[sup * (N_NODES + 1) + N_NODES] = e;
  __syncthreads();

#pragma unroll
  for (int k = 0; k < 8; ++k) {
    const int i = t + k * 1024;
    if (i < n) {
      const int rl = (ed[k].x >> 16) & 511;
      const int pos = base[rl] + atomicAdd(&off[rl], 1);
      cv[s + pos] = ed[k];
    }
  }
}

// ============================================================================
// Fused SpMM gather: one wave per row, both supports + bias + relu.
// 4 edge-groups x 16 dim-lanes x 8 dims (bf16 uint4 gather = 16B/lane).
// ============================================================================
__global__ __launch_bounds__(256) void spmm_fused_kernel(
    const int* __restrict__ rs, const int2* __restrict__ cv,
    const unsigned short* __restrict__ preb, const float* __restrict__ bias,
    float* __restrict__ out) {
  const int row = blockIdx.x * 4 + (threadIdx.x >> 6);
  const int lane = threadIdx.x & 63;
  const int g = lane >> 4;
  const int dbase = (lane & 15) << 3;

  float acc[8];
#pragma unroll
  for (int i = 0; i < 8; ++i) acc[i] = 0.f;

#pragma unroll
  for (int sup = 0; sup < 2; ++sup) {
    const int s = rs[sup * (N_NODES + 1) + row];
    const int e = rs[sup * (N_NODES + 1) + row + 1];
    const unsigned short* pb = preb + (size_t)sup * N_NODES * D;
    for (int j = s; j < e; j += 64) {
      const int nb = min(64, e - j);
      int2 ev = make_int2(0, 0);
      if (lane < nb) ev = cv[j + lane];
      for (int t4 = 0; t4 < nb; t4 += 4) {
        const int t = t4 + g;
        const int cx = __shfl(ev.x, t & 63);
        const float vt = __int_as_float(__shfl(ev.y, t & 63));
        if (t < nb) {
          const int c = cx & 0xFFFF;
          const uint4 qv = *(const uint4*)(pb + (size_t)c * D + dbase);
          const float p0 = __uint_as_float(qv.x << 16);
          const float p1 = __uint_as_float(qv.x & 0xFFFF0000u);
          const float p2 = __uint_as_float(qv.y << 16);
          const float p3 = __uint_as_float(qv.y & 0xFFFF0000u);
          const float p4 = __uint_as_float(qv.z << 16);
          const float p5 = __uint_as_float(qv.z & 0xFFFF0000u);
          const float p6 = __uint_as_float(qv.w << 16);
          const float p7 = __uint_as_float(qv.w & 0xFFFF0000u);
          acc[0] = fmaf(vt, p0, acc[0]);
          acc[1] = fmaf(vt, p1, acc[1]);
          acc[2] = fmaf(vt, p2, acc[2]);
          acc[3] = fmaf(vt, p3, acc[3]);
          acc[4] = fmaf(vt, p4, acc[4]);
          acc[5] = fmaf(vt, p5, acc[5]);
          acc[6] = fmaf(vt, p6, acc[6]);
          acc[7] = fmaf(vt, p7, acc[7]);
        }
      }
    }
  }

#pragma unroll
  for (int i = 0; i < 8; ++i) {
    acc[i] += __shfl_xor(acc[i], 16);
    acc[i] += __shfl_xor(acc[i], 32);
  }

  if (g == 0) {
    const float4 b0 = *(const float4*)(bias + dbase);
    const float4 b1 = *(const float4*)(bias + dbase + 4);
    float4 r0, r1;
    r0.x = fmaxf(acc[0] + b0.x, 0.f);
    r0.y = fmaxf(acc[1] + b0.y, 0.f);
    r0.z = fmaxf(acc[2] + b0.z, 0.f);
    r0.w = fmaxf(acc[3] + b0.w, 0.f);
    r1.x = fmaxf(acc[4] + b1.x, 0.f);
    r1.y = fmaxf(acc[5] + b1.y, 0.f);
    r1.z = fmaxf(acc[6] + b1.z, 0.f);
    r1.w = fmaxf(acc[7] + b1.w, 0.f);
    float* op = out + (size_t)row * D + dbase;
    *(float4*)op = r0;
    *(float4*)(op + 4) = r1;
  }
}

// ============================================================================
// Fallback: fp32 gemm + atomic scatter (used only if workspace too small)
// ============================================================================
__global__ __launch_bounds__(256) void gemm_f32_kernel(
    const float* __restrict__ x, const float* __restrict__ W,
    float* __restrict__ pre) {
  const int tid = threadIdx.x;
  const int nloc = (tid >> 5) << 3;
  const int d4 = (tid & 31) << 2;
  const int nbase = blockIdx.x * 64;
  __shared__ float xs[64][D];
  {
    float4* xs4 = (float4*)(&xs[0][0]);
    const float4* xg4 = (const float4*)x;
#pragma unroll
    for (int i = 0; i < 8; ++i) {
      const int idx = tid + i * 256;
      const int row = nbase + (idx >> 5);
      xs4[idx] = (row < N_NODES) ? xg4[(size_t)row * 32 + (idx & 31)]
                                 : make_float4(0.f, 0.f, 0.f, 0.f);
    }
  }
  __syncthreads();
  float4 acc[8];
#pragma unroll
  for (int i = 0; i < 8; ++i) acc[i] = make_float4(0.f, 0.f, 0.f, 0.f);
  for (int k = 0; k < D; ++k) {
    const float4 w = *(const float4*)(W + k * D + d4);
#pragma unroll
    for (int i = 0; i < 8; ++i) {
      const float xv = xs[nloc + i][k];
      acc[i].x = fmaf(xv, w.x, acc[i].x);
      acc[i].y = fmaf(xv, w.y, acc[i].y);
      acc[i].z = fmaf(xv, w.z, acc[i].z);
      acc[i].w = fmaf(xv, w.w, acc[i].w);
    }
  }
#pragma unroll
  for (int i = 0; i < 8; ++i) {
    const int n = nbase + nloc + i;
    if (n < N_NODES) *(float4*)(pre + (size_t)n * D + d4) = acc[i];
  }
}

__global__ __launch_bounds__(256) void spmm_scatter_kernel(
    const int* __restrict__ rows, const int* __restrict__ cols,
    const float* __restrict__ vals, const float* __restrict__ pre,
    float* __restrict__ out) {
  const long long idx = (long long)blockIdx.x * blockDim.x + threadIdx.x;
  const int e = (int)(idx >> 6);
  if (e >= N_EDGES) return;
  const int dd = ((int)idx & 63) << 1;
  const int r = rows[e];
  const int c = cols[e];
  const float v = vals[e];
  const float2 p = *(const float2*)(pre + (size_t)c * D + dd);
  float* outp = out + (size_t)r * D + dd;
  atomicAdd(outp + 0, v * p.x);
  atomicAdd(outp + 1, v * p.y);
}

__global__ __launch_bounds__(256) void bias_relu_kernel(
    float* __restrict__ out, const float* __restrict__ b) {
  const int idx = blockIdx.x * blockDim.x + threadIdx.x;
  float4 v = ((float4*)out)[idx];
  const float4 bb = ((const float4*)b)[idx & 31];
  v.x = fmaxf(v.x + bb.x, 0.f);
  v.y = fmaxf(v.y + bb.y, 0.f);
  v.z = fmaxf(v.z + bb.z, 0.f);
  v.w = fmaxf(v.w + bb.w, 0.f);
  ((float4*)out)[idx] = v;
}

extern "C" void kernel_launch(void* const* d_in, const int* in_sizes, int n_in,
                              void* d_out, int out_size, void* d_ws,
                              size_t ws_size, hipStream_t stream) {
  const float* x = (const float*)d_in[0];
  const float* W0 = (const float*)d_in[1];
  const float* W1 = (const float*)d_in[2];
  const float* b = (const float*)d_in[3];
  const int* rows0 = (const int*)d_in[4];
  const int* cols0 = (const int*)d_in[5];
  const float* vals0 = (const float*)d_in[6];
  const int* rows1 = (const int*)d_in[7];
  const int* cols1 = (const int*)d_in[8];
  const float* vals1 = (const float*)d_in[9];
  float* out = (float*)d_out;

  auto align_up = [](size_t v) { return (v + 255) & ~(size_t)255; };
  const size_t PREB = align_up((size_t)2 * N_NODES * D * 2);  // 25.6 MB bf16
  const size_t CV = align_up((size_t)2 * N_EDGES * 8);        // 9.6 MB
  const size_t CNT = align_up((size_t)NSEG * 4);
  const size_t FILLC = align_up((size_t)NSEG * 4);
  const size_t SBSTART = align_up((size_t)(NSEG + 1) * 4);
  const size_t RS = align_up((size_t)2 * (N_NODES + 1) * 4);  // 400 KB
  const size_t WPACK = align_up((size_t)2 * D * D * 2);       // 64 KB
  const size_t NEED = PREB + CV + CNT + FILLC + SBSTART + RS + WPACK;

  char* wsc = (char*)d_ws;

  if (ws_size >= NEED) {
    unsigned short* preb = (unsigned short*)wsc;
    int2* cv = (int2*)(wsc + PREB);
    int* cnt = (int*)(wsc + PREB + CV);
    int* fillc = (int*)(wsc + PREB + CV + CNT);
    int* sbstart = (int*)(wsc + PREB + CV + CNT + FILLC);
    int* rs = (int*)(wsc + PREB + CV + CNT + FILLC + SBSTART);
    unsigned short* wpack =
        (unsigned short*)(wsc + PREB + CV + CNT + FILLC + SBSTART + RS);

    hipMemsetAsync(cnt, 0, (size_t)NSEG * 4, stream);
    wpack_kernel<<<16, 256, 0, stream>>>(W0, W1, wpack);
    hist_kernel<<<dim3(HIST_BLOCKS, 2), 256, 0, stream>>>(rows0, rows1, cnt);
    scan196_kernel<<<1, 256, 0, stream>>>(cnt, fillc, sbstart);
    bin_kernel<<<dim3(BIN_BLOCKS, 2), 256, 0, stream>>>(
        rows0, cols0, vals0, rows1, cols1, vals1, fillc, cv);
    sort_kernel<<<dim3(SB, 2), 1024, 0, stream>>>(sbstart, cv, rs);
    gemm_mfma_kernel<<<(N_NODES + 63) / 64, 256, 0, stream>>>(x, wpack, preb);
    spmm_fused_kernel<<<N_NODES / 4, 256, 0, stream>>>(rs, cv, preb, b, out);
  } else {
    float* pre = (float*)wsc;
    hipMemsetAsync(d_out, 0, (size_t)N_NODES * D * 4, stream);
    const int scat_blocks = (N_EDGES * 64 + 255) / 256;
    gemm_f32_kernel<<<(N_NODES + 63) / 64, 256, 0, stream>>>(x, W0, pre);
    spmm_scatter_kernel<<<scat_blocks, 256, 0, stream>>>(rows0, cols0, vals0,
                                                         pre, out);
    gemm_f32_kernel<<<(N_NODES + 63) / 64, 256, 0, stream>>>(x, W1, pre);
    spmm_scatter_kernel<<<scat_blocks, 256, 0, stream>>>(rows1, cols1, vals1,
                                                         pre, out);
    bias_relu_kernel<<<(N_NODES * D / 4) / 256, 256, 0, stream>>>(out, b);
  }
}

// Round 8
// 116.813 us; speedup vs baseline: 10.6787x; 1.0165x over previous
//
#include <hip/hip_runtime.h>

#define N_NODES 50000
#define N_EDGES 600000
#define D 128
#define SB 98              // super-buckets of 512 rows (ceil(50000/512))
#define NSEG (2 * SB)      // per-support segments
#define HISTBLK 2048
#define BINBLK 4096
#define HIST_BLOCKS ((N_EDGES + HISTBLK - 1) / HISTBLK)  // 293
#define BIN_BLOCKS ((N_EDGES + BINBLK - 1) / BINBLK)     // 147
#define SPMM_BLOCKS 2048
#define SPMM_WAVES (SPMM_BLOCKS * 4)

typedef __attribute__((ext_vector_type(8))) short short8v;  // 8 bf16
typedef __attribute__((ext_vector_type(4))) float f32x4;

__device__ __forceinline__ unsigned short f2bf(float f) {
  unsigned u = __float_as_uint(f);
  return (unsigned short)((u + 0x7FFFu + ((u >> 16) & 1u)) >> 16);
}

// ============================================================================
// W prepack: Wpack[sup][ct(8)][ks(4)][lane(64)][i(8)] = bf16(W[k][d])
//   k = ks*32 + (lane>>4)*8 + i,  d = ct*16 + (lane&15)
// ============================================================================
__global__ __launch_bounds__(256) void wpack_kernel(
    const float* __restrict__ W0, const float* __restrict__ W1,
    unsigned short* __restrict__ wpack) {
  const int idx = blockIdx.x * 256 + threadIdx.x;  // 0..4095
  const int sup = idx >> 11;
  const int ct = (idx >> 8) & 7;
  const int ks = (idx >> 6) & 3;
  const int l = idx & 63;
  const int q = l >> 4;
  const int c = l & 15;
  const float* W = (sup == 0) ? W0 : W1;
  const int d = ct * 16 + c;
  unsigned short v[8];
#pragma unroll
  for (int i = 0; i < 8; ++i) {
    const int k = ks * 32 + q * 8 + i;
    v[i] = f2bf(W[k * D + d]);
  }
  *(uint4*)(wpack + (size_t)idx * 8) = *(uint4*)v;
}

// ============================================================================
// MFMA GEMM: preb[sup][n][d] = bf16( sum_k x[n][k] * W{sup}[k][d] )
// Epilogue bounces through padded LDS so global stores are coalesced dwordx4
// (the old per-lane 2-byte scattered stores were instruction/write-amp bound).
// ============================================================================
__global__ __launch_bounds__(256) void gemm_mfma_kernel(
    const float* __restrict__ x, const unsigned short* __restrict__ wpack,
    unsigned short* __restrict__ preb) {
  __shared__ unsigned short sbuf[64][136];  // +8 shorts pad: 2-way conflicts max
  const int w = threadIdx.x >> 6;
  const int lane = threadIdx.x & 63;
  const int q = lane >> 4;
  const int c = lane & 15;
  const int rowbase = blockIdx.x * 64;
  const int arow = rowbase + w * 16 + c;

  short8v afrag[4];
#pragma unroll
  for (int ks = 0; ks < 4; ++ks) {
    const int k0 = ks * 32 + q * 8;
    float4 u0 = make_float4(0.f, 0.f, 0.f, 0.f);
    float4 u1 = u0;
    if (arow < N_NODES) {
      u0 = *(const float4*)(x + (size_t)arow * D + k0);
      u1 = *(const float4*)(x + (size_t)arow * D + k0 + 4);
    }
    unsigned short a[8];
    a[0] = f2bf(u0.x); a[1] = f2bf(u0.y); a[2] = f2bf(u0.z); a[3] = f2bf(u0.w);
    a[4] = f2bf(u1.x); a[5] = f2bf(u1.y); a[6] = f2bf(u1.z); a[7] = f2bf(u1.w);
    afrag[ks] = *(const short8v*)a;
  }

  const short8v* wp = (const short8v*)wpack;
#pragma unroll
  for (int sup = 0; sup < 2; ++sup) {
    unsigned short* pb = preb + (size_t)sup * N_NODES * D;
#pragma unroll
    for (int ct = 0; ct < 8; ++ct) {
      f32x4 acc = {0.f, 0.f, 0.f, 0.f};
#pragma unroll
      for (int ks = 0; ks < 4; ++ks) {
        const short8v bfrag = wp[((sup * 8 + ct) * 4 + ks) * 64 + lane];
        acc = __builtin_amdgcn_mfma_f32_16x16x32_bf16(afrag[ks], bfrag, acc,
                                                      0, 0, 0);
      }
#pragma unroll
      for (int j = 0; j < 4; ++j)
        sbuf[w * 16 + q * 4 + j][ct * 16 + c] = f2bf(acc[j]);
    }
    __syncthreads();
    // coalesced copy-out: 1024 uint4 (64 rows x 128 shorts), 4 iters
#pragma unroll
    for (int it = 0; it < 4; ++it) {
      const int idx = threadIdx.x + it * 256;
      const int row = idx >> 4;
      const int dseg = (idx & 15) * 8;
      const uint4 v = *(const uint4*)&sbuf[row][dseg];
      const int grow = rowbase + row;
      if (grow < N_NODES) *(uint4*)(pb + (size_t)grow * D + dseg) = v;
    }
    __syncthreads();
  }
}

// ============================================================================
// Stage 1: exact super-bucket histogram (LDS-aggregated)
// ============================================================================
__global__ __launch_bounds__(256) void hist_kernel(
    const int* __restrict__ rows0, const int* __restrict__ rows1,
    int* __restrict__ cnt) {
  __shared__ int h[SB];
  const int t = threadIdx.x;
  if (t < SB) h[t] = 0;
  __syncthreads();
  const int sup = blockIdx.y;
  const int* rows = sup ? rows1 : rows0;
  int e = blockIdx.x * HISTBLK + t;
#pragma unroll
  for (int k = 0; k < HISTBLK / 256; ++k, e += 256)
    if (e < N_EDGES) atomicAdd(&h[rows[e] >> 9], 1);
  __syncthreads();
  if (t < SB && h[t] > 0) atomicAdd(&cnt[sup * SB + t], h[t]);
}

// ============================================================================
// Stage 2: exclusive scan of the 196 segment counts (one block)
// ============================================================================
__global__ __launch_bounds__(256) void scan196_kernel(
    const int* __restrict__ cnt, int* __restrict__ fillc,
    int* __restrict__ sbstart) {
  __shared__ int sh[256];
  const int t = threadIdx.x;
  const int v = (t < NSEG) ? cnt[t] : 0;
  sh[t] = v;
  __syncthreads();
  for (int off = 1; off < 256; off <<= 1) {
    const int u = (t >= off) ? sh[t - off] : 0;
    __syncthreads();
    sh[t] += u;
    __syncthreads();
  }
  if (t < NSEG) {
    const int ex = sh[t] - v;
    fillc[t] = ex;
    sbstart[t] = ex;
  }
  if (t == 0) sbstart[NSEG] = 2 * N_EDGES;
}

// ============================================================================
// Stage 3: line-dense binning (block-sorts 4096 edges by super-bucket in LDS,
// writes one contiguous global run per bucket -> full-line writes).
// cv.x = col(16) | rloc(9)<<16 | sb(7)<<25 ; cv.y = bits(val)
// ============================================================================
__global__ __launch_bounds__(256) void bin_kernel(
    const int* __restrict__ rows0, const int* __restrict__ cols0,
    const float* __restrict__ vals0, const int* __restrict__ rows1,
    const int* __restrict__ cols1, const float* __restrict__ vals1,
    int* __restrict__ fillc, int2* __restrict__ cv) {
  __shared__ int hist[SB];
  __shared__ int lsum[SB];
  __shared__ int lpos[SB];
  __shared__ int gbase[SB];
  __shared__ int2 stage[BINBLK];  // 32 KB

  const int t = threadIdx.x;
  const int sup = blockIdx.y;
  const int* rows = sup ? rows1 : rows0;
  const int* cols = sup ? cols1 : cols0;
  const float* vals = sup ? vals1 : vals0;
  const int ebase = blockIdx.x * BINBLK;
  const int nloc = min(BINBLK, N_EDGES - ebase);

  if (t < SB) hist[t] = 0;
  __syncthreads();

  int myr[16], myc[16];
  float myv[16];
#pragma unroll
  for (int k = 0; k < 16; ++k) {
    const int i = t + k * 256;
    myr[k] = -1;
    if (i < nloc) {
      myr[k] = rows[ebase + i];
      myc[k] = cols[ebase + i];
      myv[k] = vals[ebase + i];
      atomicAdd(&hist[myr[k] >> 9], 1);
    }
  }
  __syncthreads();

  if (t < SB) lsum[t] = hist[t];
  __syncthreads();
  for (int off = 1; off < SB; off <<= 1) {
    int u = 0;
    if (t < SB && t >= off) u = lsum[t - off];
    __syncthreads();
    if (t < SB) lsum[t] += u;
    __syncthreads();
  }
  if (t < SB) lpos[t] = lsum[t] - hist[t];
  __syncthreads();

#pragma unroll
  for (int k = 0; k < 16; ++k) {
    if (myr[k] >= 0) {
      const int sb = myr[k] >> 9;
      const int p = atomicAdd(&lpos[sb], 1);
      stage[p] = make_int2(myc[k] | ((myr[k] & 511) << 16) | (sb << 25),
                           __float_as_int(myv[k]));
    }
  }
  if (t < SB && hist[t] > 0)
    gbase[t] = atomicAdd(&fillc[sup * SB + t], hist[t]);
  __syncthreads();

  for (int i = t; i < nloc; i += 256) {
    const int2 ev = stage[i];
    const int sb = ((unsigned)ev.x) >> 25;
    cv[gbase[sb] + (i - (lsum[sb] - hist[sb]))] = ev;
  }
}

// ============================================================================
// Stage 4: per-super-bucket counting sort by row -> row-sorted cv + rs[].
// ============================================================================
__global__ __launch_bounds__(1024) void sort_kernel(
    const int* __restrict__ sbstart, int2* __restrict__ cv,
    int* __restrict__ rs) {
  const int sb = blockIdx.x;
  const int sup = blockIdx.y;
  const int s = sbstart[sup * SB + sb];
  const int e = sbstart[sup * SB + sb + 1];
  const int n = e - s;
  const int t = threadIdx.x;

  __shared__ int cnt[512];
  __shared__ int base[512];
  __shared__ int off[512];
  if (t < 512) {
    cnt[t] = 0;
    off[t] = 0;
  }
  __syncthreads();

  int2 ed[8];
#pragma unroll
  for (int k = 0; k < 8; ++k) {
    const int i = t + k * 1024;
    if (i < n) {
      ed[k] = cv[s + i];
      atomicAdd(&cnt[(ed[k].x >> 16) & 511], 1);
    }
  }
  __syncthreads();

  if (t < 512) base[t] = cnt[t];
  __syncthreads();
  for (int o = 1; o < 512; o <<= 1) {
    int u = 0;
    if (t < 512 && t >= o) u = base[t - o];
    __syncthreads();
    if (t < 512) base[t] += u;
    __syncthreads();
  }
  if (t < 512) {
    const int row = sb * 512 + t;
    if (row < N_NODES) rs[sup * (N_NODES + 1) + row] = s + base[t] - cnt[t];
    base[t] -= cnt[t];
  }
  if (sb == SB - 1 && t == 0) rs[sup * (N_NODES + 1) + N_NODES] = e;
  __syncthreads();

#pragma unroll
  for (int k = 0; k < 8; ++k) {
    const int i = t + k * 1024;
    if (i < n) {
      const int rl = (ed[k].x >> 16) & 511;
      const int pos = base[rl] + atomicAdd(&off[rl], 1);
      cv[s + pos] = ed[k];
    }
  }
}

// ============================================================================
// Fused SpMM gather: persistent waves (row-strided loop), both supports +
// bias + relu. 4 edge-groups x 16 dim-lanes x 8 dims. Each group loads its
// own cv[j] (uniform address within group -> HW broadcast; no ds_bpermute),
// 2x unrolled for memory-level parallelism.
// ============================================================================
__global__ __launch_bounds__(256) void spmm_fused_kernel(
    const int* __restrict__ rs, const int2* __restrict__ cv,
    const unsigned short* __restrict__ preb, const float* __restrict__ bias,
    float* __restrict__ out) {
  const int lane = threadIdx.x & 63;
  const int g = lane >> 4;
  const int dbase = (lane & 15) << 3;
  const int wid = blockIdx.x * 4 + (threadIdx.x >> 6);

  const float4 b0 = *(const float4*)(bias + dbase);
  const float4 b1 = *(const float4*)(bias + dbase + 4);

  for (int row = wid; row < N_NODES; row += SPMM_WAVES) {
    float acc[8];
#pragma unroll
    for (int i = 0; i < 8; ++i) acc[i] = 0.f;

#pragma unroll
    for (int sup = 0; sup < 2; ++sup) {
      const int s = rs[sup * (N_NODES + 1) + row];
      const int e = rs[sup * (N_NODES + 1) + row + 1];
      const unsigned short* pb = preb + (size_t)sup * N_NODES * D;
      int j = s + g;
      for (; j + 4 < e; j += 8) {
        const int2 e0 = cv[j];
        const int2 e1 = cv[j + 4];
        const uint4 q0 = *(const uint4*)(pb + (size_t)(e0.x & 0xFFFF) * D + dbase);
        const uint4 q1 = *(const uint4*)(pb + (size_t)(e1.x & 0xFFFF) * D + dbase);
        const float v0 = __int_as_float(e0.y);
        const float v1 = __int_as_float(e1.y);
        acc[0] = fmaf(v0, __uint_as_float(q0.x << 16), acc[0]);
        acc[1] = fmaf(v0, __uint_as_float(q0.x & 0xFFFF0000u), acc[1]);
        acc[2] = fmaf(v0, __uint_as_float(q0.y << 16), acc[2]);
        acc[3] = fmaf(v0, __uint_as_float(q0.y & 0xFFFF0000u), acc[3]);
        acc[4] = fmaf(v0, __uint_as_float(q0.z << 16), acc[4]);
        acc[5] = fmaf(v0, __uint_as_float(q0.z & 0xFFFF0000u), acc[5]);
        acc[6] = fmaf(v0, __uint_as_float(q0.w << 16), acc[6]);
        acc[7] = fmaf(v0, __uint_as_float(q0.w & 0xFFFF0000u), acc[7]);
        acc[0] = fmaf(v1, __uint_as_float(q1.x << 16), acc[0]);
        acc[1] = fmaf(v1, __uint_as_float(q1.x & 0xFFFF0000u), acc[1]);
        acc[2] = fmaf(v1, __uint_as_float(q1.y << 16), acc[2]);
        acc[3] = fmaf(v1, __uint_as_float(q1.y & 0xFFFF0000u), acc[3]);
        acc[4] = fmaf(v1, __uint_as_float(q1.z << 16), acc[4]);
        acc[5] = fmaf(v1, __uint_as_float(q1.z & 0xFFFF0000u), acc[5]);
        acc[6] = fmaf(v1, __uint_as_float(q1.w << 16), acc[6]);
        acc[7] = fmaf(v1, __uint_as_float(q1.w & 0xFFFF0000u), acc[7]);
      }
      if (j < e) {
        const int2 e0 = cv[j];
        const uint4 q0 = *(const uint4*)(pb + (size_t)(e0.x & 0xFFFF) * D + dbase);
        const float v0 = __int_as_float(e0.y);
        acc[0] = fmaf(v0, __uint_as_float(q0.x << 16), acc[0]);
        acc[1] = fmaf(v0, __uint_as_float(q0.x & 0xFFFF0000u), acc[1]);
        acc[2] = fmaf(v0, __uint_as_float(q0.y << 16), acc[2]);
        acc[3] = fmaf(v0, __uint_as_float(q0.y & 0xFFFF0000u), acc[3]);
        acc[4] = fmaf(v0, __uint_as_float(q0.z << 16), acc[4]);
        acc[5] = fmaf(v0, __uint_as_float(q0.z & 0xFFFF0000u), acc[5]);
        acc[6] = fmaf(v0, __uint_as_float(q0.w << 16), acc[6]);
        acc[7] = fmaf(v0, __uint_as_float(q0.w & 0xFFFF0000u), acc[7]);
      }
    }

#pragma unroll
    for (int i = 0; i < 8; ++i) {
      acc[i] += __shfl_xor(acc[i], 16);
      acc[i] += __shfl_xor(acc[i], 32);
    }

    if (g == 0) {
      float4 r0, r1;
      r0.x = fmaxf(acc[0] + b0.x, 0.f);
      r0.y = fmaxf(acc[1] + b0.y, 0.f);
      r0.z = fmaxf(acc[2] + b0.z, 0.f);
      r0.w = fmaxf(acc[3] + b0.w, 0.f);
      r1.x = fmaxf(acc[4] + b1.x, 0.f);
      r1.y = fmaxf(acc[5] + b1.y, 0.f);
      r1.z = fmaxf(acc[6] + b1.z, 0.f);
      r1.w = fmaxf(acc[7] + b1.w, 0.f);
      float* op = out + (size_t)row * D + dbase;
      *(float4*)op = r0;
      *(float4*)(op + 4) = r1;
    }
  }
}

// ============================================================================
// Fallback: fp32 gemm + atomic scatter (used only if workspace too small)
// ============================================================================
__global__ __launch_bounds__(256) void gemm_f32_kernel(
    const float* __restrict__ x, const float* __restrict__ W,
    float* __restrict__ pre) {
  const int tid = threadIdx.x;
  const int nloc = (tid >> 5) << 3;
  const int d4 = (tid & 31) << 2;
  const int nbase = blockIdx.x * 64;
  __shared__ float xs[64][D];
  {
    float4* xs4 = (float4*)(&xs[0][0]);
    const float4* xg4 = (const float4*)x;
#pragma unroll
    for (int i = 0; i < 8; ++i) {
      const int idx = tid + i * 256;
      const int row = nbase + (idx >> 5);
      xs4[idx] = (row < N_NODES) ? xg4[(size_t)row * 32 + (idx & 31)]
                                 : make_float4(0.f, 0.f, 0.f, 0.f);
    }
  }
  __syncthreads();
  float4 acc[8];
#pragma unroll
  for (int i = 0; i < 8; ++i) acc[i] = make_float4(0.f, 0.f, 0.f, 0.f);
  for (int k = 0; k < D; ++k) {
    const float4 w = *(const float4*)(W + k * D + d4);
#pragma unroll
    for (int i = 0; i < 8; ++i) {
      const float xv = xs[nloc + i][k];
      acc[i].x = fmaf(xv, w.x, acc[i].x);
      acc[i].y = fmaf(xv, w.y, acc[i].y);
      acc[i].z = fmaf(xv, w.z, acc[i].z);
      acc[i].w = fmaf(xv, w.w, acc[i].w);
    }
  }
#pragma unroll
  for (int i = 0; i < 8; ++i) {
    const int n = nbase + nloc + i;
    if (n < N_NODES) *(float4*)(pre + (size_t)n * D + d4) = acc[i];
  }
}

__global__ __launch_bounds__(256) void spmm_scatter_kernel(
    const int* __restrict__ rows, const int* __restrict__ cols,
    const float* __restrict__ vals, const float* __restrict__ pre,
    float* __restrict__ out) {
  const long long idx = (long long)blockIdx.x * blockDim.x + threadIdx.x;
  const int e = (int)(idx >> 6);
  if (e >= N_EDGES) return;
  const int dd = ((int)idx & 63) << 1;
  const int r = rows[e];
  const int c = cols[e];
  const float v = vals[e];
  const float2 p = *(const float2*)(pre + (size_t)c * D + dd);
  float* outp = out + (size_t)r * D + dd;
  atomicAdd(outp + 0, v * p.x);
  atomicAdd(outp + 1, v * p.y);
}

__global__ __launch_bounds__(256) void bias_relu_kernel(
    float* __restrict__ out, const float* __restrict__ b) {
  const int idx = blockIdx.x * blockDim.x + threadIdx.x;
  float4 v = ((float4*)out)[idx];
  const float4 bb = ((const float4*)b)[idx & 31];
  v.x = fmaxf(v.x + bb.x, 0.f);
  v.y = fmaxf(v.y + bb.y, 0.f);
  v.z = fmaxf(v.z + bb.z, 0.f);
  v.w = fmaxf(v.w + bb.w, 0.f);
  ((float4*)out)[idx] = v;
}

extern "C" void kernel_launch(void* const* d_in, const int* in_sizes, int n_in,
                              void* d_out, int out_size, void* d_ws,
                              size_t ws_size, hipStream_t stream) {
  const float* x = (const float*)d_in[0];
  const float* W0 = (const float*)d_in[1];
  const float* W1 = (const float*)d_in[2];
  const float* b = (const float*)d_in[3];
  const int* rows0 = (const int*)d_in[4];
  const int* cols0 = (const int*)d_in[5];
  const float* vals0 = (const float*)d_in[6];
  const int* rows1 = (const int*)d_in[7];
  const int* cols1 = (const int*)d_in[8];
  const float* vals1 = (const float*)d_in[9];
  float* out = (float*)d_out;

  auto align_up = [](size_t v) { return (v + 255) & ~(size_t)255; };
  const size_t PREB = align_up((size_t)2 * N_NODES * D * 2);  // 25.6 MB bf16
  const size_t CV = align_up((size_t)2 * N_EDGES * 8);        // 9.6 MB
  const size_t CNT = align_up((size_t)NSEG * 4);
  const size_t FILLC = align_up((size_t)NSEG * 4);
  const size_t SBSTART = align_up((size_t)(NSEG + 1) * 4);
  const size_t RS = align_up((size_t)2 * (N_NODES + 1) * 4);  // 400 KB
  const size_t WPACK = align_up((size_t)2 * D * D * 2);       // 64 KB
  const size_t NEED = PREB + CV + CNT + FILLC + SBSTART + RS + WPACK;

  char* wsc = (char*)d_ws;

  if (ws_size >= NEED) {
    unsigned short* preb = (unsigned short*)wsc;
    int2* cv = (int2*)(wsc + PREB);
    int* cnt = (int*)(wsc + PREB + CV);
    int* fillc = (int*)(wsc + PREB + CV + CNT);
    int* sbstart = (int*)(wsc + PREB + CV + CNT + FILLC);
    int* rs = (int*)(wsc + PREB + CV + CNT + FILLC + SBSTART);
    unsigned short* wpack =
        (unsigned short*)(wsc + PREB + CV + CNT + FILLC + SBSTART + RS);

    hipMemsetAsync(cnt, 0, (size_t)NSEG * 4, stream);
    wpack_kernel<<<16, 256, 0, stream>>>(W0, W1, wpack);
    hist_kernel<<<dim3(HIST_BLOCKS, 2), 256, 0, stream>>>(rows0, rows1, cnt);
    scan196_kernel<<<1, 256, 0, stream>>>(cnt, fillc, sbstart);
    bin_kernel<<<dim3(BIN_BLOCKS, 2), 256, 0, stream>>>(
        rows0, cols0, vals0, rows1, cols1, vals1, fillc, cv);
    sort_kernel<<<dim3(SB, 2), 1024, 0, stream>>>(sbstart, cv, rs);
    gemm_mfma_kernel<<<(N_NODES + 63) / 64, 256, 0, stream>>>(x, wpack, preb);
    spmm_fused_kernel<<<SPMM_BLOCKS, 256, 0, stream>>>(rs, cv, preb, b, out);
  } else {
    float* pre = (float*)wsc;
    hipMemsetAsync(d_out, 0, (size_t)N_NODES * D * 4, stream);
    const int scat_blocks = (N_EDGES * 64 + 255) / 256;
    gemm_f32_kernel<<<(N_NODES + 63) / 64, 256, 0, stream>>>(x, W0, pre);
    spmm_scatter_kernel<<<scat_blocks, 256, 0, stream>>>(rows0, cols0, vals0,
                                                         pre, out);
    gemm_f32_kernel<<<(N_NODES + 63) / 64, 256, 0, stream>>>(x, W1, pre);
    spmm_scatter_kernel<<<scat_blocks, 256, 0, stream>>>(rows1, cols1, vals1,
                                                         pre, out);
    bias_relu_kernel<<<(N_NODES * D / 4) / 256, 256, 0, stream>>>(out, b);
  }
}

// Round 9
// 113.030 us; speedup vs baseline: 11.0361x; 1.0335x over previous
//
#include <hip/hip_runtime.h>

#define N_NODES 50000
#define N_EDGES 600000
#define D 128
#define SB 98              // super-buckets of 512 rows (ceil(50000/512))
#define NSEG (2 * SB)      // per-support segments
#define HISTBLK 2048
#define BINBLK 4096
#define HIST_BLOCKS ((N_EDGES + HISTBLK - 1) / HISTBLK)  // 293
#define BIN_BLOCKS ((N_EDGES + BINBLK - 1) / BINBLK)     // 147
#define SPMM_BLOCKS 2048
#define SPMM_WAVES (SPMM_BLOCKS * 4)

typedef __attribute__((ext_vector_type(8))) short short8v;  // 8 bf16
typedef __attribute__((ext_vector_type(4))) float f32x4;

__device__ __forceinline__ unsigned short f2bf(float f) {
  unsigned u = __float_as_uint(f);
  return (unsigned short)((u + 0x7FFFu + ((u >> 16) & 1u)) >> 16);
}

// ============================================================================
// Fused Stage 1: super-bucket histogram (blocks 0..292) + W prepack (blocks
// 293..300). Independent work in one launch.
//   Wpack[sup][ct(8)][ks(4)][lane(64)][i(8)] = bf16(W[k][d])
//   k = ks*32 + (lane>>4)*8 + i,  d = ct*16 + (lane&15)
// ============================================================================
__global__ __launch_bounds__(256) void histpack_kernel(
    const int* __restrict__ rows0, const int* __restrict__ rows1,
    int* __restrict__ cnt, const float* __restrict__ W0,
    const float* __restrict__ W1, unsigned short* __restrict__ wpack) {
  const int t = threadIdx.x;
  if (blockIdx.x >= HIST_BLOCKS) {
    const int idx =
        ((blockIdx.x - HIST_BLOCKS) + 8 * blockIdx.y) * 256 + t;  // 0..4095
    const int sup = idx >> 11;
    const int ct = (idx >> 8) & 7;
    const int ks = (idx >> 6) & 3;
    const int l = idx & 63;
    const int q = l >> 4;
    const int c = l & 15;
    const float* W = (sup == 0) ? W0 : W1;
    const int d = ct * 16 + c;
    unsigned short v[8];
#pragma unroll
    for (int i = 0; i < 8; ++i) {
      const int k = ks * 32 + q * 8 + i;
      v[i] = f2bf(W[k * D + d]);
    }
    *(uint4*)(wpack + (size_t)idx * 8) = *(uint4*)v;
    return;
  }
  __shared__ int h[SB];
  if (t < SB) h[t] = 0;
  __syncthreads();
  const int sup = blockIdx.y;
  const int* rows = sup ? rows1 : rows0;
  int e = blockIdx.x * HISTBLK + t;
#pragma unroll
  for (int k = 0; k < HISTBLK / 256; ++k, e += 256)
    if (e < N_EDGES) atomicAdd(&h[rows[e] >> 9], 1);
  __syncthreads();
  if (t < SB && h[t] > 0) atomicAdd(&cnt[sup * SB + t], h[t]);
}

// ============================================================================
// Stage 2: exclusive scan of the 196 segment counts — single wave, no barriers
// ============================================================================
__global__ __launch_bounds__(64) void scan196_kernel(
    const int* __restrict__ cnt, int* __restrict__ fillc,
    int* __restrict__ sbstart) {
  const int t = threadIdx.x;  // 0..63, 4 values per lane
  int v[4];
  int ssum = 0;
#pragma unroll
  for (int k = 0; k < 4; ++k) {
    const int g = t * 4 + k;
    v[k] = (g < NSEG) ? cnt[g] : 0;
    ssum += v[k];
  }
  int run = ssum;
#pragma unroll
  for (int off = 1; off < 64; off <<= 1) {
    const int u = __shfl_up(run, off);
    if (t >= off) run += u;
  }
  int excl = run - ssum;
#pragma unroll
  for (int k = 0; k < 4; ++k) {
    const int g = t * 4 + k;
    if (g < NSEG) {
      fillc[g] = excl;
      sbstart[g] = excl;
    }
    excl += v[k];
  }
  if (t == 63) sbstart[NSEG] = 2 * N_EDGES;
}

// ============================================================================
// Stage 3: line-dense binning (block-sorts 4096 edges by super-bucket in LDS,
// writes one contiguous global run per bucket -> full-line writes).
// cv.x = col(16) | rloc(9)<<16 | sb(7)<<25 ; cv.y = bits(val)
// ============================================================================
__global__ __launch_bounds__(256) void bin_kernel(
    const int* __restrict__ rows0, const int* __restrict__ cols0,
    const float* __restrict__ vals0, const int* __restrict__ rows1,
    const int* __restrict__ cols1, const float* __restrict__ vals1,
    int* __restrict__ fillc, int2* __restrict__ cv) {
  __shared__ int hist[SB];
  __shared__ int lstart[SB];  // exclusive prefix (local)
  __shared__ int lpos[SB];    // bump counters
  __shared__ int gbase[SB];   // global run bases
  __shared__ int2 stage[BINBLK];  // 32 KB

  const int t = threadIdx.x;
  const int sup = blockIdx.y;
  const int* rows = sup ? rows1 : rows0;
  const int* cols = sup ? cols1 : cols0;
  const float* vals = sup ? vals1 : vals0;
  const int ebase = blockIdx.x * BINBLK;
  const int nloc = min(BINBLK, N_EDGES - ebase);

  if (t < SB) hist[t] = 0;
  __syncthreads();

  int myr[16], myc[16];
  float myv[16];
#pragma unroll
  for (int k = 0; k < 16; ++k) {
    const int i = t + k * 256;
    myr[k] = -1;
    if (i < nloc) {
      myr[k] = rows[ebase + i];
      myc[k] = cols[ebase + i];
      myv[k] = vals[ebase + i];
      atomicAdd(&hist[myr[k] >> 9], 1);
    }
  }
  __syncthreads();

  // wave-0 exclusive scan of hist[98] (2 values/lane), no barriers inside
  if (t < 64) {
    const int g0 = 2 * t, g1 = 2 * t + 1;
    const int v0 = (g0 < SB) ? hist[g0] : 0;
    const int v1 = (g1 < SB) ? hist[g1] : 0;
    const int ssum = v0 + v1;
    int run = ssum;
#pragma unroll
    for (int off = 1; off < 64; off <<= 1) {
      const int u = __shfl_up(run, off);
      if (t >= off) run += u;
    }
    const int excl = run - ssum;
    if (g0 < SB) {
      lstart[g0] = excl;
      lpos[g0] = excl;
    }
    if (g1 < SB) {
      lstart[g1] = excl + v0;
      lpos[g1] = excl + v0;
    }
  }
  __syncthreads();

#pragma unroll
  for (int k = 0; k < 16; ++k) {
    if (myr[k] >= 0) {
      const int sb = myr[k] >> 9;
      const int p = atomicAdd(&lpos[sb], 1);
      stage[p] = make_int2(myc[k] | ((myr[k] & 511) << 16) | (sb << 25),
                           __float_as_int(myv[k]));
    }
  }
  if (t < SB && hist[t] > 0)
    gbase[t] = atomicAdd(&fillc[sup * SB + t], hist[t]);
  __syncthreads();

  for (int i = t; i < nloc; i += 256) {
    const int2 ev = stage[i];
    const int sb = ((unsigned)ev.x) >> 25;
    cv[gbase[sb] + (i - lstart[sb])] = ev;
  }
}

// ============================================================================
// Stage 4: per-super-bucket counting sort by row -> row-sorted cv + rs[].
// 512-wide scan done by wave 0 in registers (no Hillis-Steele barriers).
// ============================================================================
__global__ __launch_bounds__(1024) void sort_kernel(
    const int* __restrict__ sbstart, int2* __restrict__ cv,
    int* __restrict__ rs) {
  const int sb = blockIdx.x;
  const int sup = blockIdx.y;
  const int s = sbstart[sup * SB + sb];
  const int e = sbstart[sup * SB + sb + 1];
  const int n = e - s;
  const int t = threadIdx.x;

  __shared__ int cnt[512];
  __shared__ int base[512];  // exclusive prefix
  __shared__ int off[512];
  if (t < 512) {
    cnt[t] = 0;
    off[t] = 0;
  }
  __syncthreads();

  int2 ed[8];
#pragma unroll
  for (int k = 0; k < 8; ++k) {
    const int i = t + k * 1024;
    if (i < n) {
      ed[k] = cv[s + i];
      atomicAdd(&cnt[(ed[k].x >> 16) & 511], 1);
    }
  }
  __syncthreads();

  // wave-0 exclusive scan of cnt[512]: 8 values/lane + butterfly on lane sums
  if (t < 64) {
    int v[8];
    int ssum = 0;
#pragma unroll
    for (int k = 0; k < 8; ++k) {
      v[k] = cnt[t * 8 + k];
      ssum += v[k];
    }
    int run = ssum;
#pragma unroll
    for (int off2 = 1; off2 < 64; off2 <<= 1) {
      const int u = __shfl_up(run, off2);
      if (t >= off2) run += u;
    }
    int excl = run - ssum;
#pragma unroll
    for (int k = 0; k < 8; ++k) {
      base[t * 8 + k] = excl;
      excl += v[k];
    }
  }
  __syncthreads();

  if (t < 512) {
    const int row = sb * 512 + t;
    if (row < N_NODES) rs[sup * (N_NODES + 1) + row] = s + base[t];
  }
  if (sb == SB - 1 && t == 0) rs[sup * (N_NODES + 1) + N_NODES] = e;

#pragma unroll
  for (int k = 0; k < 8; ++k) {
    const int i = t + k * 1024;
    if (i < n) {
      const int rl = (ed[k].x >> 16) & 511;
      const int pos = base[rl] + atomicAdd(&off[rl], 1);
      cv[s + pos] = ed[k];
    }
  }
}

// ============================================================================
// MFMA GEMM: preb[sup][n][d] = bf16( sum_k x[n][k] * W{sup}[k][d] )
// Epilogue bounces through padded LDS -> coalesced dwordx4 stores.
// ============================================================================
__global__ __launch_bounds__(256) void gemm_mfma_kernel(
    const float* __restrict__ x, const unsigned short* __restrict__ wpack,
    unsigned short* __restrict__ preb) {
  __shared__ unsigned short sbuf[64][136];
  const int w = threadIdx.x >> 6;
  const int lane = threadIdx.x & 63;
  const int q = lane >> 4;
  const int c = lane & 15;
  const int rowbase = blockIdx.x * 64;
  const int arow = rowbase + w * 16 + c;

  short8v afrag[4];
#pragma unroll
  for (int ks = 0; ks < 4; ++ks) {
    const int k0 = ks * 32 + q * 8;
    float4 u0 = make_float4(0.f, 0.f, 0.f, 0.f);
    float4 u1 = u0;
    if (arow < N_NODES) {
      u0 = *(const float4*)(x + (size_t)arow * D + k0);
      u1 = *(const float4*)(x + (size_t)arow * D + k0 + 4);
    }
    unsigned short a[8];
    a[0] = f2bf(u0.x); a[1] = f2bf(u0.y); a[2] = f2bf(u0.z); a[3] = f2bf(u0.w);
    a[4] = f2bf(u1.x); a[5] = f2bf(u1.y); a[6] = f2bf(u1.z); a[7] = f2bf(u1.w);
    afrag[ks] = *(const short8v*)a;
  }

  const short8v* wp = (const short8v*)wpack;
#pragma unroll
  for (int sup = 0; sup < 2; ++sup) {
    unsigned short* pb = preb + (size_t)sup * N_NODES * D;
#pragma unroll
    for (int ct = 0; ct < 8; ++ct) {
      f32x4 acc = {0.f, 0.f, 0.f, 0.f};
#pragma unroll
      for (int ks = 0; ks < 4; ++ks) {
        const short8v bfrag = wp[((sup * 8 + ct) * 4 + ks) * 64 + lane];
        acc = __builtin_amdgcn_mfma_f32_16x16x32_bf16(afrag[ks], bfrag, acc,
                                                      0, 0, 0);
      }
#pragma unroll
      for (int j = 0; j < 4; ++j)
        sbuf[w * 16 + q * 4 + j][ct * 16 + c] = f2bf(acc[j]);
    }
    __syncthreads();
#pragma unroll
    for (int it = 0; it < 4; ++it) {
      const int idx = threadIdx.x + it * 256;
      const int row = idx >> 4;
      const int dseg = (idx & 15) * 8;
      const uint4 v = *(const uint4*)&sbuf[row][dseg];
      const int grow = rowbase + row;
      if (grow < N_NODES) *(uint4*)(pb + (size_t)grow * D + dseg) = v;
    }
    __syncthreads();
  }
}

// ============================================================================
// Fused SpMM gather: persistent waves, both supports + bias + relu.
// 4 edge-groups x 16 dim-lanes x 8 dims; group-uniform cv loads; 2x unroll.
// ============================================================================
__global__ __launch_bounds__(256) void spmm_fused_kernel(
    const int* __restrict__ rs, const int2* __restrict__ cv,
    const unsigned short* __restrict__ preb, const float* __restrict__ bias,
    float* __restrict__ out) {
  const int lane = threadIdx.x & 63;
  const int g = lane >> 4;
  const int dbase = (lane & 15) << 3;
  const int wid = blockIdx.x * 4 + (threadIdx.x >> 6);

  const float4 b0 = *(const float4*)(bias + dbase);
  const float4 b1 = *(const float4*)(bias + dbase + 4);

  for (int row = wid; row < N_NODES; row += SPMM_WAVES) {
    float acc[8];
#pragma unroll
    for (int i = 0; i < 8; ++i) acc[i] = 0.f;

#pragma unroll
    for (int sup = 0; sup < 2; ++sup) {
      const int s = rs[sup * (N_NODES + 1) + row];
      const int e = rs[sup * (N_NODES + 1) + row + 1];
      const unsigned short* pb = preb + (size_t)sup * N_NODES * D;
      int j = s + g;
      for (; j + 4 < e; j += 8) {
        const int2 e0 = cv[j];
        const int2 e1 = cv[j + 4];
        const uint4 q0 = *(const uint4*)(pb + (size_t)(e0.x & 0xFFFF) * D + dbase);
        const uint4 q1 = *(const uint4*)(pb + (size_t)(e1.x & 0xFFFF) * D + dbase);
        const float v0 = __int_as_float(e0.y);
        const float v1 = __int_as_float(e1.y);
        acc[0] = fmaf(v0, __uint_as_float(q0.x << 16), acc[0]);
        acc[1] = fmaf(v0, __uint_as_float(q0.x & 0xFFFF0000u), acc[1]);
        acc[2] = fmaf(v0, __uint_as_float(q0.y << 16), acc[2]);
        acc[3] = fmaf(v0, __uint_as_float(q0.y & 0xFFFF0000u), acc[3]);
        acc[4] = fmaf(v0, __uint_as_float(q0.z << 16), acc[4]);
        acc[5] = fmaf(v0, __uint_as_float(q0.z & 0xFFFF0000u), acc[5]);
        acc[6] = fmaf(v0, __uint_as_float(q0.w << 16), acc[6]);
        acc[7] = fmaf(v0, __uint_as_float(q0.w & 0xFFFF0000u), acc[7]);
        acc[0] = fmaf(v1, __uint_as_float(q1.x << 16), acc[0]);
        acc[1] = fmaf(v1, __uint_as_float(q1.x & 0xFFFF0000u), acc[1]);
        acc[2] = fmaf(v1, __uint_as_float(q1.y << 16), acc[2]);
        acc[3] = fmaf(v1, __uint_as_float(q1.y & 0xFFFF0000u), acc[3]);
        acc[4] = fmaf(v1, __uint_as_float(q1.z << 16), acc[4]);
        acc[5] = fmaf(v1, __uint_as_float(q1.z & 0xFFFF0000u), acc[5]);
        acc[6] = fmaf(v1, __uint_as_float(q1.w << 16), acc[6]);
        acc[7] = fmaf(v1, __uint_as_float(q1.w & 0xFFFF0000u), acc[7]);
      }
      if (j < e) {
        const int2 e0 = cv[j];
        const uint4 q0 = *(const uint4*)(pb + (size_t)(e0.x & 0xFFFF) * D + dbase);
        const float v0 = __int_as_float(e0.y);
        acc[0] = fmaf(v0, __uint_as_float(q0.x << 16), acc[0]);
        acc[1] = fmaf(v0, __uint_as_float(q0.x & 0xFFFF0000u), acc[1]);
        acc[2] = fmaf(v0, __uint_as_float(q0.y << 16), acc[2]);
        acc[3] = fmaf(v0, __uint_as_float(q0.y & 0xFFFF0000u), acc[3]);
        acc[4] = fmaf(v0, __uint_as_float(q0.z << 16), acc[4]);
        acc[5] = fmaf(v0, __uint_as_float(q0.z & 0xFFFF0000u), acc[5]);
        acc[6] = fmaf(v0, __uint_as_float(q0.w << 16), acc[6]);
        acc[7] = fmaf(v0, __uint_as_float(q0.w & 0xFFFF0000u), acc[7]);
      }
    }

#pragma unroll
    for (int i = 0; i < 8; ++i) {
      acc[i] += __shfl_xor(acc[i], 16);
      acc[i] += __shfl_xor(acc[i], 32);
    }

    if (g == 0) {
      float4 r0, r1;
      r0.x = fmaxf(acc[0] + b0.x, 0.f);
      r0.y = fmaxf(acc[1] + b0.y, 0.f);
      r0.z = fmaxf(acc[2] + b0.z, 0.f);
      r0.w = fmaxf(acc[3] + b0.w, 0.f);
      r1.x = fmaxf(acc[4] + b1.x, 0.f);
      r1.y = fmaxf(acc[5] + b1.y, 0.f);
      r1.z = fmaxf(acc[6] + b1.z, 0.f);
      r1.w = fmaxf(acc[7] + b1.w, 0.f);
      float* op = out + (size_t)row * D + dbase;
      *(float4*)op = r0;
      *(float4*)(op + 4) = r1;
    }
  }
}

// ============================================================================
// Fallback: fp32 gemm + atomic scatter (used only if workspace too small)
// ============================================================================
__global__ __launch_bounds__(256) void gemm_f32_kernel(
    const float* __restrict__ x, const float* __restrict__ W,
    float* __restrict__ pre) {
  const int tid = threadIdx.x;
  const int nloc = (tid >> 5) << 3;
  const int d4 = (tid & 31) << 2;
  const int nbase = blockIdx.x * 64;
  __shared__ float xs[64][D];
  {
    float4* xs4 = (float4*)(&xs[0][0]);
    const float4* xg4 = (const float4*)x;
#pragma unroll
    for (int i = 0; i < 8; ++i) {
      const int idx = tid + i * 256;
      const int row = nbase + (idx >> 5);
      xs4[idx] = (row < N_NODES) ? xg4[(size_t)row * 32 + (idx & 31)]
                                 : make_float4(0.f, 0.f, 0.f, 0.f);
    }
  }
  __syncthreads();
  float4 acc[8];
#pragma unroll
  for (int i = 0; i < 8; ++i) acc[i] = make_float4(0.f, 0.f, 0.f, 0.f);
  for (int k = 0; k < D; ++k) {
    const float4 w = *(const float4*)(W + k * D + d4);
#pragma unroll
    for (int i = 0; i < 8; ++i) {
      const float xv = xs[nloc + i][k];
      acc[i].x = fmaf(xv, w.x, acc[i].x);
      acc[i].y = fmaf(xv, w.y, acc[i].y);
      acc[i].z = fmaf(xv, w.z, acc[i].z);
      acc[i].w = fmaf(xv, w.w, acc[i].w);
    }
  }
#pragma unroll
  for (int i = 0; i < 8; ++i) {
    const int n = nbase + nloc + i;
    if (n < N_NODES) *(float4*)(pre + (size_t)n * D + d4) = acc[i];
  }
}

__global__ __launch_bounds__(256) void spmm_scatter_kernel(
    const int* __restrict__ rows, const int* __restrict__ cols,
    const float* __restrict__ vals, const float* __restrict__ pre,
    float* __restrict__ out) {
  const long long idx = (long long)blockIdx.x * blockDim.x + threadIdx.x;
  const int e = (int)(idx >> 6);
  if (e >= N_EDGES) return;
  const int dd = ((int)idx & 63) << 1;
  const int r = rows[e];
  const int c = cols[e];
  const float v = vals[e];
  const float2 p = *(const float2*)(pre + (size_t)c * D + dd);
  float* outp = out + (size_t)r * D + dd;
  atomicAdd(outp + 0, v * p.x);
  atomicAdd(outp + 1, v * p.y);
}

__global__ __launch_bounds__(256) void bias_relu_kernel(
    float* __restrict__ out, const float* __restrict__ b) {
  const int idx = blockIdx.x * blockDim.x + threadIdx.x;
  float4 v = ((float4*)out)[idx];
  const float4 bb = ((const float4*)b)[idx & 31];
  v.x = fmaxf(v.x + bb.x, 0.f);
  v.y = fmaxf(v.y + bb.y, 0.f);
  v.z = fmaxf(v.z + bb.z, 0.f);
  v.w = fmaxf(v.w + bb.w, 0.f);
  ((float4*)out)[idx] = v;
}

extern "C" void kernel_launch(void* const* d_in, const int* in_sizes, int n_in,
                              void* d_out, int out_size, void* d_ws,
                              size_t ws_size, hipStream_t stream) {
  const float* x = (const float*)d_in[0];
  const float* W0 = (const float*)d_in[1];
  const float* W1 = (const float*)d_in[2];
  const float* b = (const float*)d_in[3];
  const int* rows0 = (const int*)d_in[4];
  const int* cols0 = (const int*)d_in[5];
  const float* vals0 = (const float*)d_in[6];
  const int* rows1 = (const int*)d_in[7];
  const int* cols1 = (const int*)d_in[8];
  const float* vals1 = (const float*)d_in[9];
  float* out = (float*)d_out;

  auto align_up = [](size_t v) { return (v + 255) & ~(size_t)255; };
  const size_t PREB = align_up((size_t)2 * N_NODES * D * 2);  // 25.6 MB bf16
  const size_t CV = align_up((size_t)2 * N_EDGES * 8);        // 9.6 MB
  const size_t CNT = align_up((size_t)NSEG * 4);
  const size_t FILLC = align_up((size_t)NSEG * 4);
  const size_t SBSTART = align_up((size_t)(NSEG + 1) * 4);
  const size_t RS = align_up((size_t)2 * (N_NODES + 1) * 4);  // 400 KB
  const size_t WPACK = align_up((size_t)2 * D * D * 2);       // 64 KB
  const size_t NEED = PREB + CV + CNT + FILLC + SBSTART + RS + WPACK;

  char* wsc = (char*)d_ws;

  if (ws_size >= NEED) {
    unsigned short* preb = (unsigned short*)wsc;
    int2* cv = (int2*)(wsc + PREB);
    int* cnt = (int*)(wsc + PREB + CV);
    int* fillc = (int*)(wsc + PREB + CV + CNT);
    int* sbstart = (int*)(wsc + PREB + CV + CNT + FILLC);
    int* rs = (int*)(wsc + PREB + CV + CNT + FILLC + SBSTART);
    unsigned short* wpack =
        (unsigned short*)(wsc + PREB + CV + CNT + FILLC + SBSTART + RS);

    hipMemsetAsync(cnt, 0, (size_t)NSEG * 4, stream);
    histpack_kernel<<<dim3(HIST_BLOCKS + 8, 2), 256, 0, stream>>>(
        rows0, rows1, cnt, W0, W1, wpack);
    scan196_kernel<<<1, 64, 0, stream>>>(cnt, fillc, sbstart);
    bin_kernel<<<dim3(BIN_BLOCKS, 2), 256, 0, stream>>>(
        rows0, cols0, vals0, rows1, cols1, vals1, fillc, cv);
    sort_kernel<<<dim3(SB, 2), 1024, 0, stream>>>(sbstart, cv, rs);
    gemm_mfma_kernel<<<(N_NODES + 63) / 64, 256, 0, stream>>>(x, wpack, preb);
    spmm_fused_kernel<<<SPMM_BLOCKS, 256, 0, stream>>>(rs, cv, preb, b, out);
  } else {
    float* pre = (float*)wsc;
    hipMemsetAsync(d_out, 0, (size_t)N_NODES * D * 4, stream);
    const int scat_blocks = (N_EDGES * 64 + 255) / 256;
    gemm_f32_kernel<<<(N_NODES + 63) / 64, 256, 0, stream>>>(x, W0, pre);
    spmm_scatter_kernel<<<scat_blocks, 256, 0, stream>>>(rows0, cols0, vals0,
                                                         pre, out);
    gemm_f32_kernel<<<(N_NODES + 63) / 64, 256, 0, stream>>>(x, W1, pre);
    spmm_scatter_kernel<<<scat_blocks, 256, 0, stream>>>(rows1, cols1, vals1,
                                                         pre, out);
    bias_relu_kernel<<<(N_NODES * D / 4) / 256, 256, 0, stream>>>(out, b);
  }
}

// Round 10
// 102.843 us; speedup vs baseline: 12.1292x; 1.0990x over previous
//
#include <hip/hip_runtime.h>

#define N_NODES 50000
#define N_EDGES 600000
#define D 128
#define SB 98              // super-buckets of 512 rows (ceil(50000/512))
#define NSEG (2 * SB)      // per-support segments
#define HISTBLK 2048
#define BINBLK 4096
#define HIST_BLOCKS ((N_EDGES + HISTBLK - 1) / HISTBLK)  // 293
#define BIN_BLOCKS ((N_EDGES + BINBLK - 1) / BINBLK)     // 147
#define GEMM_BLOCKS ((N_NODES + 63) / 64)                // 782
#define SPMM_BLOCKS 2048
#define SPMM_WAVES (SPMM_BLOCKS * 4)

typedef __attribute__((ext_vector_type(8))) short short8v;  // 8 bf16
typedef __attribute__((ext_vector_type(4))) float f32x4;

__device__ __forceinline__ unsigned short f2bf(float f) {
  unsigned u = __float_as_uint(f);
  return (unsigned short)((u + 0x7FFFu + ((u >> 16) & 1u)) >> 16);
}

// ============================================================================
// Fused Stage 1: super-bucket histogram (blocks 0..292) + W prepack (blocks
// 293..300).
//   Wpack[sup][ct(8)][ks(4)][lane(64)][i(8)] = bf16(W[k][d])
//   k = ks*32 + (lane>>4)*8 + i,  d = ct*16 + (lane&15)
// ============================================================================
__global__ __launch_bounds__(256) void histpack_kernel(
    const int* __restrict__ rows0, const int* __restrict__ rows1,
    int* __restrict__ cnt, const float* __restrict__ W0,
    const float* __restrict__ W1, unsigned short* __restrict__ wpack) {
  const int t = threadIdx.x;
  if (blockIdx.x >= HIST_BLOCKS) {
    const int idx =
        ((blockIdx.x - HIST_BLOCKS) + 8 * blockIdx.y) * 256 + t;  // 0..4095
    const int sup = idx >> 11;
    const int ct = (idx >> 8) & 7;
    const int ks = (idx >> 6) & 3;
    const int l = idx & 63;
    const int q = l >> 4;
    const int c = l & 15;
    const float* W = (sup == 0) ? W0 : W1;
    const int d = ct * 16 + c;
    unsigned short v[8];
#pragma unroll
    for (int i = 0; i < 8; ++i) {
      const int k = ks * 32 + q * 8 + i;
      v[i] = f2bf(W[k * D + d]);
    }
    *(uint4*)(wpack + (size_t)idx * 8) = *(uint4*)v;
    return;
  }
  __shared__ int h[SB];
  if (t < SB) h[t] = 0;
  __syncthreads();
  const int sup = blockIdx.y;
  const int* rows = sup ? rows1 : rows0;
  int e = blockIdx.x * HISTBLK + t;
#pragma unroll
  for (int k = 0; k < HISTBLK / 256; ++k, e += 256)
    if (e < N_EDGES) atomicAdd(&h[rows[e] >> 9], 1);
  __syncthreads();
  if (t < SB && h[t] > 0) atomicAdd(&cnt[sup * SB + t], h[t]);
}

// ============================================================================
// Stage 2: exclusive scan of the 196 segment counts — single wave, no barriers
// ============================================================================
__global__ __launch_bounds__(64) void scan196_kernel(
    const int* __restrict__ cnt, int* __restrict__ fillc,
    int* __restrict__ sbstart) {
  const int t = threadIdx.x;  // 0..63, 4 values per lane
  int v[4];
  int ssum = 0;
#pragma unroll
  for (int k = 0; k < 4; ++k) {
    const int g = t * 4 + k;
    v[k] = (g < NSEG) ? cnt[g] : 0;
    ssum += v[k];
  }
  int run = ssum;
#pragma unroll
  for (int off = 1; off < 64; off <<= 1) {
    const int u = __shfl_up(run, off);
    if (t >= off) run += u;
  }
  int excl = run - ssum;
#pragma unroll
  for (int k = 0; k < 4; ++k) {
    const int g = t * 4 + k;
    if (g < NSEG) {
      fillc[g] = excl;
      sbstart[g] = excl;
    }
    excl += v[k];
  }
  if (t == 63) sbstart[NSEG] = 2 * N_EDGES;
}

// ============================================================================
// Fused Stage 3: bin (blocks 0..293) + MFMA GEMM (blocks 294..1075).
// Independent chains — bin consumes fillc (scan output), gemm consumes wpack
// (histpack output) — co-scheduled in one launch to overlap.
// LDS is a union: bin needs 34.3 KB, gemm 17.4 KB.
// bin: block-sorts 4096 edges by super-bucket in LDS, writes one contiguous
//      global run per bucket (full-line writes).
//      cv.x = col(16) | rloc(9)<<16 | sb(7)<<25 ; cv.y = bits(val)
// gemm: preb[sup][n][d] = bf16(sum_k x[n][k]*W{sup}[k][d]), LDS-bounced
//       coalesced dwordx4 stores.
// ============================================================================
union BinGemmSmem {
  struct {
    int hist[SB];
    int lstart[SB];
    int lpos[SB];
    int gbase[SB];
    int2 stage[BINBLK];  // 32 KB
  } bin;
  unsigned short sbuf[64][136];  // 17.4 KB
};

__global__ __launch_bounds__(256) void bingemm_kernel(
    const int* __restrict__ rows0, const int* __restrict__ cols0,
    const float* __restrict__ vals0, const int* __restrict__ rows1,
    const int* __restrict__ cols1, const float* __restrict__ vals1,
    int* __restrict__ fillc, int2* __restrict__ cv,
    const float* __restrict__ x, const unsigned short* __restrict__ wpack,
    unsigned short* __restrict__ preb) {
  __shared__ BinGemmSmem sm;
  const int t = threadIdx.x;
  const int bx = blockIdx.x;

  if (bx >= 2 * BIN_BLOCKS) {
    // ---------------- GEMM path ----------------
    const int gb = bx - 2 * BIN_BLOCKS;
    const int w = t >> 6;
    const int lane = t & 63;
    const int q = lane >> 4;
    const int c = lane & 15;
    const int rowbase = gb * 64;
    const int arow = rowbase + w * 16 + c;

    short8v afrag[4];
#pragma unroll
    for (int ks = 0; ks < 4; ++ks) {
      const int k0 = ks * 32 + q * 8;
      float4 u0 = make_float4(0.f, 0.f, 0.f, 0.f);
      float4 u1 = u0;
      if (arow < N_NODES) {
        u0 = *(const float4*)(x + (size_t)arow * D + k0);
        u1 = *(const float4*)(x + (size_t)arow * D + k0 + 4);
      }
      unsigned short a[8];
      a[0] = f2bf(u0.x); a[1] = f2bf(u0.y);
      a[2] = f2bf(u0.z); a[3] = f2bf(u0.w);
      a[4] = f2bf(u1.x); a[5] = f2bf(u1.y);
      a[6] = f2bf(u1.z); a[7] = f2bf(u1.w);
      afrag[ks] = *(const short8v*)a;
    }

    const short8v* wp = (const short8v*)wpack;
#pragma unroll
    for (int sup = 0; sup < 2; ++sup) {
      unsigned short* pb = preb + (size_t)sup * N_NODES * D;
#pragma unroll
      for (int ct = 0; ct < 8; ++ct) {
        f32x4 acc = {0.f, 0.f, 0.f, 0.f};
#pragma unroll
        for (int ks = 0; ks < 4; ++ks) {
          const short8v bfrag = wp[((sup * 8 + ct) * 4 + ks) * 64 + lane];
          acc = __builtin_amdgcn_mfma_f32_16x16x32_bf16(afrag[ks], bfrag, acc,
                                                        0, 0, 0);
        }
#pragma unroll
        for (int j = 0; j < 4; ++j)
          sm.sbuf[w * 16 + q * 4 + j][ct * 16 + c] = f2bf(acc[j]);
      }
      __syncthreads();
#pragma unroll
      for (int it = 0; it < 4; ++it) {
        const int idx = t + it * 256;
        const int row = idx >> 4;
        const int dseg = (idx & 15) * 8;
        const uint4 v = *(const uint4*)&sm.sbuf[row][dseg];
        const int grow = rowbase + row;
        if (grow < N_NODES) *(uint4*)(pb + (size_t)grow * D + dseg) = v;
      }
      __syncthreads();
    }
    return;
  }

  // ---------------- bin path ----------------
  const int sup = (bx >= BIN_BLOCKS) ? 1 : 0;
  const int bb = bx - sup * BIN_BLOCKS;
  const int* rows = sup ? rows1 : rows0;
  const int* cols = sup ? cols1 : cols0;
  const float* vals = sup ? vals1 : vals0;
  const int ebase = bb * BINBLK;
  const int nloc = min(BINBLK, N_EDGES - ebase);

  if (t < SB) sm.bin.hist[t] = 0;
  __syncthreads();

  int myr[16], myc[16];
  float myv[16];
#pragma unroll
  for (int k = 0; k < 16; ++k) {
    const int i = t + k * 256;
    myr[k] = -1;
    if (i < nloc) {
      myr[k] = rows[ebase + i];
      myc[k] = cols[ebase + i];
      myv[k] = vals[ebase + i];
      atomicAdd(&sm.bin.hist[myr[k] >> 9], 1);
    }
  }
  __syncthreads();

  // wave-0 exclusive scan of hist[98] (2 values/lane), no barriers inside
  if (t < 64) {
    const int g0 = 2 * t, g1 = 2 * t + 1;
    const int v0 = (g0 < SB) ? sm.bin.hist[g0] : 0;
    const int v1 = (g1 < SB) ? sm.bin.hist[g1] : 0;
    const int ssum = v0 + v1;
    int run = ssum;
#pragma unroll
    for (int off = 1; off < 64; off <<= 1) {
      const int u = __shfl_up(run, off);
      if (t >= off) run += u;
    }
    const int excl = run - ssum;
    if (g0 < SB) {
      sm.bin.lstart[g0] = excl;
      sm.bin.lpos[g0] = excl;
    }
    if (g1 < SB) {
      sm.bin.lstart[g1] = excl + v0;
      sm.bin.lpos[g1] = excl + v0;
    }
  }
  __syncthreads();

#pragma unroll
  for (int k = 0; k < 16; ++k) {
    if (myr[k] >= 0) {
      const int sb = myr[k] >> 9;
      const int p = atomicAdd(&sm.bin.lpos[sb], 1);
      sm.bin.stage[p] =
          make_int2(myc[k] | ((myr[k] & 511) << 16) | (sb << 25),
                    __float_as_int(myv[k]));
    }
  }
  if (t < SB && sm.bin.hist[t] > 0)
    sm.bin.gbase[t] = atomicAdd(&fillc[sup * SB + t], sm.bin.hist[t]);
  __syncthreads();

  for (int i = t; i < nloc; i += 256) {
    const int2 ev = sm.bin.stage[i];
    const int sb = ((unsigned)ev.x) >> 25;
    cv[sm.bin.gbase[sb] + (i - sm.bin.lstart[sb])] = ev;
  }
}

// ============================================================================
// Stage 4: per-super-bucket counting sort by row -> row-sorted cv + rs[].
// 512-wide scan done by wave 0 in registers.
// ============================================================================
__global__ __launch_bounds__(1024) void sort_kernel(
    const int* __restrict__ sbstart, int2* __restrict__ cv,
    int* __restrict__ rs) {
  const int sb = blockIdx.x;
  const int sup = blockIdx.y;
  const int s = sbstart[sup * SB + sb];
  const int e = sbstart[sup * SB + sb + 1];
  const int n = e - s;
  const int t = threadIdx.x;

  __shared__ int cnt[512];
  __shared__ int base[512];  // exclusive prefix
  __shared__ int off[512];
  if (t < 512) {
    cnt[t] = 0;
    off[t] = 0;
  }
  __syncthreads();

  int2 ed[8];
#pragma unroll
  for (int k = 0; k < 8; ++k) {
    const int i = t + k * 1024;
    if (i < n) {
      ed[k] = cv[s + i];
      atomicAdd(&cnt[(ed[k].x >> 16) & 511], 1);
    }
  }
  __syncthreads();

  if (t < 64) {
    int v[8];
    int ssum = 0;
#pragma unroll
    for (int k = 0; k < 8; ++k) {
      v[k] = cnt[t * 8 + k];
      ssum += v[k];
    }
    int run = ssum;
#pragma unroll
    for (int off2 = 1; off2 < 64; off2 <<= 1) {
      const int u = __shfl_up(run, off2);
      if (t >= off2) run += u;
    }
    int excl = run - ssum;
#pragma unroll
    for (int k = 0; k < 8; ++k) {
      base[t * 8 + k] = excl;
      excl += v[k];
    }
  }
  __syncthreads();

  if (t < 512) {
    const int row = sb * 512 + t;
    if (row < N_NODES) rs[sup * (N_NODES + 1) + row] = s + base[t];
  }
  if (sb == SB - 1 && t == 0) rs[sup * (N_NODES + 1) + N_NODES] = e;

#pragma unroll
  for (int k = 0; k < 8; ++k) {
    const int i = t + k * 1024;
    if (i < n) {
      const int rl = (ed[k].x >> 16) & 511;
      const int pos = base[rl] + atomicAdd(&off[rl], 1);
      cv[s + pos] = ed[k];
    }
  }
}

// ============================================================================
// Fused SpMM gather: persistent waves, both supports + bias + relu.
// 4 edge-groups x 16 dim-lanes x 8 dims; group-uniform cv loads; 2x unroll.
// ============================================================================
__global__ __launch_bounds__(256) void spmm_fused_kernel(
    const int* __restrict__ rs, const int2* __restrict__ cv,
    const unsigned short* __restrict__ preb, const float* __restrict__ bias,
    float* __restrict__ out) {
  const int lane = threadIdx.x & 63;
  const int g = lane >> 4;
  const int dbase = (lane & 15) << 3;
  const int wid = blockIdx.x * 4 + (threadIdx.x >> 6);

  const float4 b0 = *(const float4*)(bias + dbase);
  const float4 b1 = *(const float4*)(bias + dbase + 4);

  for (int row = wid; row < N_NODES; row += SPMM_WAVES) {
    float acc[8];
#pragma unroll
    for (int i = 0; i < 8; ++i) acc[i] = 0.f;

#pragma unroll
    for (int sup = 0; sup < 2; ++sup) {
      const int s = rs[sup * (N_NODES + 1) + row];
      const int e = rs[sup * (N_NODES + 1) + row + 1];
      const unsigned short* pb = preb + (size_t)sup * N_NODES * D;
      int j = s + g;
      for (; j + 4 < e; j += 8) {
        const int2 e0 = cv[j];
        const int2 e1 = cv[j + 4];
        const uint4 q0 = *(const uint4*)(pb + (size_t)(e0.x & 0xFFFF) * D + dbase);
        const uint4 q1 = *(const uint4*)(pb + (size_t)(e1.x & 0xFFFF) * D + dbase);
        const float v0 = __int_as_float(e0.y);
        const float v1 = __int_as_float(e1.y);
        acc[0] = fmaf(v0, __uint_as_float(q0.x << 16), acc[0]);
        acc[1] = fmaf(v0, __uint_as_float(q0.x & 0xFFFF0000u), acc[1]);
        acc[2] = fmaf(v0, __uint_as_float(q0.y << 16), acc[2]);
        acc[3] = fmaf(v0, __uint_as_float(q0.y & 0xFFFF0000u), acc[3]);
        acc[4] = fmaf(v0, __uint_as_float(q0.z << 16), acc[4]);
        acc[5] = fmaf(v0, __uint_as_float(q0.z & 0xFFFF0000u), acc[5]);
        acc[6] = fmaf(v0, __uint_as_float(q0.w << 16), acc[6]);
        acc[7] = fmaf(v0, __uint_as_float(q0.w & 0xFFFF0000u), acc[7]);
        acc[0] = fmaf(v1, __uint_as_float(q1.x << 16), acc[0]);
        acc[1] = fmaf(v1, __uint_as_float(q1.x & 0xFFFF0000u), acc[1]);
        acc[2] = fmaf(v1, __uint_as_float(q1.y << 16), acc[2]);
        acc[3] = fmaf(v1, __uint_as_float(q1.y & 0xFFFF0000u), acc[3]);
        acc[4] = fmaf(v1, __uint_as_float(q1.z << 16), acc[4]);
        acc[5] = fmaf(v1, __uint_as_float(q1.z & 0xFFFF0000u), acc[5]);
        acc[6] = fmaf(v1, __uint_as_float(q1.w << 16), acc[6]);
        acc[7] = fmaf(v1, __uint_as_float(q1.w & 0xFFFF0000u), acc[7]);
      }
      if (j < e) {
        const int2 e0 = cv[j];
        const uint4 q0 = *(const uint4*)(pb + (size_t)(e0.x & 0xFFFF) * D + dbase);
        const float v0 = __int_as_float(e0.y);
        acc[0] = fmaf(v0, __uint_as_float(q0.x << 16), acc[0]);
        acc[1] = fmaf(v0, __uint_as_float(q0.x & 0xFFFF0000u), acc[1]);
        acc[2] = fmaf(v0, __uint_as_float(q0.y << 16), acc[2]);
        acc[3] = fmaf(v0, __uint_as_float(q0.y & 0xFFFF0000u), acc[3]);
        acc[4] = fmaf(v0, __uint_as_float(q0.z << 16), acc[4]);
        acc[5] = fmaf(v0, __uint_as_float(q0.z & 0xFFFF0000u), acc[5]);
        acc[6] = fmaf(v0, __uint_as_float(q0.w << 16), acc[6]);
        acc[7] = fmaf(v0, __uint_as_float(q0.w & 0xFFFF0000u), acc[7]);
      }
    }

#pragma unroll
    for (int i = 0; i < 8; ++i) {
      acc[i] += __shfl_xor(acc[i], 16);
      acc[i] += __shfl_xor(acc[i], 32);
    }

    if (g == 0) {
      float4 r0, r1;
      r0.x = fmaxf(acc[0] + b0.x, 0.f);
      r0.y = fmaxf(acc[1] + b0.y, 0.f);
      r0.z = fmaxf(acc[2] + b0.z, 0.f);
      r0.w = fmaxf(acc[3] + b0.w, 0.f);
      r1.x = fmaxf(acc[4] + b1.x, 0.f);
      r1.y = fmaxf(acc[5] + b1.y, 0.f);
      r1.z = fmaxf(acc[6] + b1.z, 0.f);
      r1.w = fmaxf(acc[7] + b1.w, 0.f);
      float* op = out + (size_t)row * D + dbase;
      *(float4*)op = r0;
      *(float4*)(op + 4) = r1;
    }
  }
}

// ============================================================================
// Fallback: fp32 gemm + atomic scatter (used only if workspace too small)
// ============================================================================
__global__ __launch_bounds__(256) void gemm_f32_kernel(
    const float* __restrict__ x, const float* __restrict__ W,
    float* __restrict__ pre) {
  const int tid = threadIdx.x;
  const int nloc = (tid >> 5) << 3;
  const int d4 = (tid & 31) << 2;
  const int nbase = blockIdx.x * 64;
  __shared__ float xs[64][D];
  {
    float4* xs4 = (float4*)(&xs[0][0]);
    const float4* xg4 = (const float4*)x;
#pragma unroll
    for (int i = 0; i < 8; ++i) {
      const int idx = tid + i * 256;
      const int row = nbase + (idx >> 5);
      xs4[idx] = (row < N_NODES) ? xg4[(size_t)row * 32 + (idx & 31)]
                                 : make_float4(0.f, 0.f, 0.f, 0.f);
    }
  }
  __syncthreads();
  float4 acc[8];
#pragma unroll
  for (int i = 0; i < 8; ++i) acc[i] = make_float4(0.f, 0.f, 0.f, 0.f);
  for (int k = 0; k < D; ++k) {
    const float4 w = *(const float4*)(W + k * D + d4);
#pragma unroll
    for (int i = 0; i < 8; ++i) {
      const float xv = xs[nloc + i][k];
      acc[i].x = fmaf(xv, w.x, acc[i].x);
      acc[i].y = fmaf(xv, w.y, acc[i].y);
      acc[i].z = fmaf(xv, w.z, acc[i].z);
      acc[i].w = fmaf(xv, w.w, acc[i].w);
    }
  }
#pragma unroll
  for (int i = 0; i < 8; ++i) {
    const int n = nbase + nloc + i;
    if (n < N_NODES) *(float4*)(pre + (size_t)n * D + d4) = acc[i];
  }
}

__global__ __launch_bounds__(256) void spmm_scatter_kernel(
    const int* __restrict__ rows, const int* __restrict__ cols,
    const float* __restrict__ vals, const float* __restrict__ pre,
    float* __restrict__ out) {
  const long long idx = (long long)blockIdx.x * blockDim.x + threadIdx.x;
  const int e = (int)(idx >> 6);
  if (e >= N_EDGES) return;
  const int dd = ((int)idx & 63) << 1;
  const int r = rows[e];
  const int c = cols[e];
  const float v = vals[e];
  const float2 p = *(const float2*)(pre + (size_t)c * D + dd);
  float* outp = out + (size_t)r * D + dd;
  atomicAdd(outp + 0, v * p.x);
  atomicAdd(outp + 1, v * p.y);
}

__global__ __launch_bounds__(256) void bias_relu_kernel(
    float* __restrict__ out, const float* __restrict__ b) {
  const int idx = blockIdx.x * blockDim.x + threadIdx.x;
  float4 v = ((float4*)out)[idx];
  const float4 bb = ((const float4*)b)[idx & 31];
  v.x = fmaxf(v.x + bb.x, 0.f);
  v.y = fmaxf(v.y + bb.y, 0.f);
  v.z = fmaxf(v.z + bb.z, 0.f);
  v.w = fmaxf(v.w + bb.w, 0.f);
  ((float4*)out)[idx] = v;
}

extern "C" void kernel_launch(void* const* d_in, const int* in_sizes, int n_in,
                              void* d_out, int out_size, void* d_ws,
                              size_t ws_size, hipStream_t stream) {
  const float* x = (const float*)d_in[0];
  const float* W0 = (const float*)d_in[1];
  const float* W1 = (const float*)d_in[2];
  const float* b = (const float*)d_in[3];
  const int* rows0 = (const int*)d_in[4];
  const int* cols0 = (const int*)d_in[5];
  const float* vals0 = (const float*)d_in[6];
  const int* rows1 = (const int*)d_in[7];
  const int* cols1 = (const int*)d_in[8];
  const float* vals1 = (const float*)d_in[9];
  float* out = (float*)d_out;

  auto align_up = [](size_t v) { return (v + 255) & ~(size_t)255; };
  const size_t PREB = align_up((size_t)2 * N_NODES * D * 2);  // 25.6 MB bf16
  const size_t CV = align_up((size_t)2 * N_EDGES * 8);        // 9.6 MB
  const size_t CNT = align_up((size_t)NSEG * 4);
  const size_t FILLC = align_up((size_t)NSEG * 4);
  const size_t SBSTART = align_up((size_t)(NSEG + 1) * 4);
  const size_t RS = align_up((size_t)2 * (N_NODES + 1) * 4);  // 400 KB
  const size_t WPACK = align_up((size_t)2 * D * D * 2);       // 64 KB
  const size_t NEED = PREB + CV + CNT + FILLC + SBSTART + RS + WPACK;

  char* wsc = (char*)d_ws;

  if (ws_size >= NEED) {
    unsigned short* preb = (unsigned short*)wsc;
    int2* cv = (int2*)(wsc + PREB);
    int* cnt = (int*)(wsc + PREB + CV);
    int* fillc = (int*)(wsc + PREB + CV + CNT);
    int* sbstart = (int*)(wsc + PREB + CV + CNT + FILLC);
    int* rs = (int*)(wsc + PREB + CV + CNT + FILLC + SBSTART);
    unsigned short* wpack =
        (unsigned short*)(wsc + PREB + CV + CNT + FILLC + SBSTART + RS);

    hipMemsetAsync(cnt, 0, (size_t)NSEG * 4, stream);
    histpack_kernel<<<dim3(HIST_BLOCKS + 8, 2), 256, 0, stream>>>(
        rows0, rows1, cnt, W0, W1, wpack);
    scan196_kernel<<<1, 64, 0, stream>>>(cnt, fillc, sbstart);
    bingemm_kernel<<<2 * BIN_BLOCKS + GEMM_BLOCKS, 256, 0, stream>>>(
        rows0, cols0, vals0, rows1, cols1, vals1, fillc, cv, x, wpack, preb);
    sort_kernel<<<dim3(SB, 2), 1024, 0, stream>>>(sbstart, cv, rs);
    spmm_fused_kernel<<<SPMM_BLOCKS, 256, 0, stream>>>(rs, cv, preb, b, out);
  } else {
    float* pre = (float*)wsc;
    hipMemsetAsync(d_out, 0, (size_t)N_NODES * D * 4, stream);
    const int scat_blocks = (N_EDGES * 64 + 255) / 256;
    gemm_f32_kernel<<<GEMM_BLOCKS, 256, 0, stream>>>(x, W0, pre);
    spmm_scatter_kernel<<<scat_blocks, 256, 0, stream>>>(rows0, cols0, vals0,
                                                         pre, out);
    gemm_f32_kernel<<<GEMM_BLOCKS, 256, 0, stream>>>(x, W1, pre);
    spmm_scatter_kernel<<<scat_blocks, 256, 0, stream>>>(rows1, cols1, vals1,
                                                         pre, out);
    bias_relu_kernel<<<(N_NODES * D / 4) / 256, 256, 0, stream>>>(out, b);
  }
}

// Round 11
// 89.139 us; speedup vs baseline: 13.9940x; 1.1537x over previous
//
#include <hip/hip_runtime.h>

#define N_NODES 50000
#define N_EDGES 600000
#define D 128
#define SB 98              // super-buckets of 512 rows (ceil(50000/512))
#define NSEG (2 * SB)      // per-support segments
#define CAP 8192           // fixed per-segment capacity (mean 6144 + 26 sigma)
#define HISTBLK 2048
#define BINBLK 4096
#define HIST_BLOCKS ((N_EDGES + HISTBLK - 1) / HISTBLK)  // 293
#define BIN_BLOCKS ((N_EDGES + BINBLK - 1) / BINBLK)     // 147
#define GEMM_BLOCKS ((N_NODES + 63) / 64)                // 782
#define SPMM_BLOCKS 2048
#define SPMM_WAVES (SPMM_BLOCKS * 4)

typedef __attribute__((ext_vector_type(8))) short short8v;  // 8 bf16
typedef __attribute__((ext_vector_type(4))) float f32x4;

__device__ __forceinline__ unsigned short f2bf(float f) {
  unsigned u = __float_as_uint(f);
  return (unsigned short)((u + 0x7FFFu + ((u >> 16) & 1u)) >> 16);
}

// ============================================================================
// W-fragment pack (device helper): Wpack[sup][ct(8)][ks(4)][lane(64)][i(8)]
//   k = ks*32 + (lane>>4)*8 + i,  d = ct*16 + (lane&15)
// ============================================================================
__device__ __forceinline__ void wpack_one(int idx, const float* __restrict__ W0,
                                          const float* __restrict__ W1,
                                          unsigned short* __restrict__ wpack) {
  const int sup = idx >> 11;
  const int ct = (idx >> 8) & 7;
  const int ks = (idx >> 6) & 3;
  const int l = idx & 63;
  const int q = l >> 4;
  const int c = l & 15;
  const float* W = (sup == 0) ? W0 : W1;
  const int d = ct * 16 + c;
  unsigned short v[8];
#pragma unroll
  for (int i = 0; i < 8; ++i) {
    const int k = ks * 32 + q * 8 + i;
    v[i] = f2bf(W[k * D + d]);
  }
  *(uint4*)(wpack + (size_t)idx * 8) = *(uint4*)v;
}

// ============================================================================
// Tier A init: blocks 0..15 pack W, block 16 zeroes fillc.
// ============================================================================
__global__ __launch_bounds__(256) void init_kernel(
    const float* __restrict__ W0, const float* __restrict__ W1,
    unsigned short* __restrict__ wpack, int* __restrict__ fillc) {
  const int t = threadIdx.x;
  if (blockIdx.x == 16) {
    if (t < NSEG) fillc[t] = 0;
    return;
  }
  wpack_one(blockIdx.x * 256 + t, W0, W1, wpack);
}

// ============================================================================
// Tier B stage 1: super-bucket histogram + W prepack (round-10 path)
// ============================================================================
__global__ __launch_bounds__(256) void histpack_kernel(
    const int* __restrict__ rows0, const int* __restrict__ rows1,
    int* __restrict__ cnt, const float* __restrict__ W0,
    const float* __restrict__ W1, unsigned short* __restrict__ wpack) {
  const int t = threadIdx.x;
  if (blockIdx.x >= HIST_BLOCKS) {
    wpack_one(((blockIdx.x - HIST_BLOCKS) + 8 * blockIdx.y) * 256 + t, W0, W1,
              wpack);
    return;
  }
  __shared__ int h[SB];
  if (t < SB) h[t] = 0;
  __syncthreads();
  const int sup = blockIdx.y;
  const int* rows = sup ? rows1 : rows0;
  int e = blockIdx.x * HISTBLK + t;
#pragma unroll
  for (int k = 0; k < HISTBLK / 256; ++k, e += 256)
    if (e < N_EDGES) atomicAdd(&h[rows[e] >> 9], 1);
  __syncthreads();
  if (t < SB && h[t] > 0) atomicAdd(&cnt[sup * SB + t], h[t]);
}

// ============================================================================
// Tier B stage 2: exclusive scan of the 196 segment counts — single wave
// ============================================================================
__global__ __launch_bounds__(64) void scan196_kernel(
    const int* __restrict__ cnt, int* __restrict__ fillc,
    int* __restrict__ sbstart) {
  const int t = threadIdx.x;
  int v[4];
  int ssum = 0;
#pragma unroll
  for (int k = 0; k < 4; ++k) {
    const int g = t * 4 + k;
    v[k] = (g < NSEG) ? cnt[g] : 0;
    ssum += v[k];
  }
  int run = ssum;
#pragma unroll
  for (int off = 1; off < 64; off <<= 1) {
    const int u = __shfl_up(run, off);
    if (t >= off) run += u;
  }
  int excl = run - ssum;
#pragma unroll
  for (int k = 0; k < 4; ++k) {
    const int g = t * 4 + k;
    if (g < NSEG) {
      fillc[g] = excl;
      sbstart[g] = excl;
    }
    excl += v[k];
  }
  if (t == 63) sbstart[NSEG] = 2 * N_EDGES;
}

// ============================================================================
// Fused bin + MFMA GEMM (one launch; independent chains co-scheduled).
// CAPPED: bin base = seg*CAP + bump(count).  Exact: base = bump(fillc=scan).
// cv.x = col(16) | rloc(9)<<16 | sb(7)<<25 ; cv.y = bits(val)
// ============================================================================
union BinGemmSmem {
  struct {
    int hist[SB];
    int lstart[SB];
    int lpos[SB];
    int gbase[SB];
    int2 stage[BINBLK];  // 32 KB
  } bin;
  unsigned short sbuf[64][136];  // 17.4 KB
};

template <bool CAPPED>
__global__ __launch_bounds__(256) void bingemm_kernel(
    const int* __restrict__ rows0, const int* __restrict__ cols0,
    const float* __restrict__ vals0, const int* __restrict__ rows1,
    const int* __restrict__ cols1, const float* __restrict__ vals1,
    int* __restrict__ fillc, int2* __restrict__ cv,
    const float* __restrict__ x, const unsigned short* __restrict__ wpack,
    unsigned short* __restrict__ preb) {
  __shared__ BinGemmSmem sm;
  const int t = threadIdx.x;
  const int bx = blockIdx.x;

  if (bx >= 2 * BIN_BLOCKS) {
    // ---------------- GEMM path ----------------
    const int gb = bx - 2 * BIN_BLOCKS;
    const int w = t >> 6;
    const int lane = t & 63;
    const int q = lane >> 4;
    const int c = lane & 15;
    const int rowbase = gb * 64;
    const int arow = rowbase + w * 16 + c;

    short8v afrag[4];
#pragma unroll
    for (int ks = 0; ks < 4; ++ks) {
      const int k0 = ks * 32 + q * 8;
      float4 u0 = make_float4(0.f, 0.f, 0.f, 0.f);
      float4 u1 = u0;
      if (arow < N_NODES) {
        u0 = *(const float4*)(x + (size_t)arow * D + k0);
        u1 = *(const float4*)(x + (size_t)arow * D + k0 + 4);
      }
      unsigned short a[8];
      a[0] = f2bf(u0.x); a[1] = f2bf(u0.y);
      a[2] = f2bf(u0.z); a[3] = f2bf(u0.w);
      a[4] = f2bf(u1.x); a[5] = f2bf(u1.y);
      a[6] = f2bf(u1.z); a[7] = f2bf(u1.w);
      afrag[ks] = *(const short8v*)a;
    }

    const short8v* wp = (const short8v*)wpack;
#pragma unroll
    for (int sup = 0; sup < 2; ++sup) {
      unsigned short* pb = preb + (size_t)sup * N_NODES * D;
#pragma unroll
      for (int ct = 0; ct < 8; ++ct) {
        f32x4 acc = {0.f, 0.f, 0.f, 0.f};
#pragma unroll
        for (int ks = 0; ks < 4; ++ks) {
          const short8v bfrag = wp[((sup * 8 + ct) * 4 + ks) * 64 + lane];
          acc = __builtin_amdgcn_mfma_f32_16x16x32_bf16(afrag[ks], bfrag, acc,
                                                        0, 0, 0);
        }
#pragma unroll
        for (int j = 0; j < 4; ++j)
          sm.sbuf[w * 16 + q * 4 + j][ct * 16 + c] = f2bf(acc[j]);
      }
      __syncthreads();
#pragma unroll
      for (int it = 0; it < 4; ++it) {
        const int idx = t + it * 256;
        const int row = idx >> 4;
        const int dseg = (idx & 15) * 8;
        const uint4 v = *(const uint4*)&sm.sbuf[row][dseg];
        const int grow = rowbase + row;
        if (grow < N_NODES) *(uint4*)(pb + (size_t)grow * D + dseg) = v;
      }
      __syncthreads();
    }
    return;
  }

  // ---------------- bin path ----------------
  const int sup = (bx >= BIN_BLOCKS) ? 1 : 0;
  const int bb = bx - sup * BIN_BLOCKS;
  const int* rows = sup ? rows1 : rows0;
  const int* cols = sup ? cols1 : cols0;
  const float* vals = sup ? vals1 : vals0;
  const int ebase = bb * BINBLK;
  const int nloc = min(BINBLK, N_EDGES - ebase);

  if (t < SB) sm.bin.hist[t] = 0;
  __syncthreads();

  int myr[16], myc[16];
  float myv[16];
#pragma unroll
  for (int k = 0; k < 16; ++k) {
    const int i = t + k * 256;
    myr[k] = -1;
    if (i < nloc) {
      myr[k] = rows[ebase + i];
      myc[k] = cols[ebase + i];
      myv[k] = vals[ebase + i];
      atomicAdd(&sm.bin.hist[myr[k] >> 9], 1);
    }
  }
  __syncthreads();

  if (t < 64) {
    const int g0 = 2 * t, g1 = 2 * t + 1;
    const int v0 = (g0 < SB) ? sm.bin.hist[g0] : 0;
    const int v1 = (g1 < SB) ? sm.bin.hist[g1] : 0;
    const int ssum = v0 + v1;
    int run = ssum;
#pragma unroll
    for (int off = 1; off < 64; off <<= 1) {
      const int u = __shfl_up(run, off);
      if (t >= off) run += u;
    }
    const int excl = run - ssum;
    if (g0 < SB) {
      sm.bin.lstart[g0] = excl;
      sm.bin.lpos[g0] = excl;
    }
    if (g1 < SB) {
      sm.bin.lstart[g1] = excl + v0;
      sm.bin.lpos[g1] = excl + v0;
    }
  }
  __syncthreads();

#pragma unroll
  for (int k = 0; k < 16; ++k) {
    if (myr[k] >= 0) {
      const int sb = myr[k] >> 9;
      const int p = atomicAdd(&sm.bin.lpos[sb], 1);
      sm.bin.stage[p] =
          make_int2(myc[k] | ((myr[k] & 511) << 16) | (sb << 25),
                    __float_as_int(myv[k]));
    }
  }
  if (t < SB && sm.bin.hist[t] > 0) {
    const int seg = sup * SB + t;
    const int bump = atomicAdd(&fillc[seg], sm.bin.hist[t]);
    sm.bin.gbase[t] = (CAPPED ? seg * CAP : 0) + bump;
  }
  __syncthreads();

  for (int i = t; i < nloc; i += 256) {
    const int2 ev = sm.bin.stage[i];
    const int sb = ((unsigned)ev.x) >> 25;
    cv[sm.bin.gbase[sb] + (i - sm.bin.lstart[sb])] = ev;
  }
}

// ============================================================================
// Per-super-bucket counting sort by row -> row-sorted cv + rs_start/rs_end.
// CAPPED: segment at seg*CAP with count fillc[seg]. Exact: sbstart bounds.
// ============================================================================
template <bool CAPPED>
__global__ __launch_bounds__(1024) void sort_kernel(
    const int* __restrict__ sbstart, const int* __restrict__ fillc,
    int2* __restrict__ cv, int* __restrict__ rs_s, int* __restrict__ rs_e) {
  const int sb = blockIdx.x;
  const int sup = blockIdx.y;
  const int seg = sup * SB + sb;
  const int s = CAPPED ? seg * CAP : sbstart[seg];
  const int n = CAPPED ? fillc[seg] : (sbstart[seg + 1] - s);
  const int t = threadIdx.x;

  __shared__ int cnt[512];
  __shared__ int base[512];
  __shared__ int off[512];
  if (t < 512) {
    cnt[t] = 0;
    off[t] = 0;
  }
  __syncthreads();

  int2 ed[8];
#pragma unroll
  for (int k = 0; k < 8; ++k) {
    const int i = t + k * 1024;
    if (i < n) {
      ed[k] = cv[s + i];
      atomicAdd(&cnt[(ed[k].x >> 16) & 511], 1);
    }
  }
  __syncthreads();

  if (t < 64) {
    int v[8];
    int ssum = 0;
#pragma unroll
    for (int k = 0; k < 8; ++k) {
      v[k] = cnt[t * 8 + k];
      ssum += v[k];
    }
    int run = ssum;
#pragma unroll
    for (int off2 = 1; off2 < 64; off2 <<= 1) {
      const int u = __shfl_up(run, off2);
      if (t >= off2) run += u;
    }
    int excl = run - ssum;
#pragma unroll
    for (int k = 0; k < 8; ++k) {
      base[t * 8 + k] = excl;
      excl += v[k];
    }
  }
  __syncthreads();

  if (t < 512) {
    const int row = sb * 512 + t;
    if (row < N_NODES) {
      rs_s[sup * N_NODES + row] = s + base[t];
      rs_e[sup * N_NODES + row] = s + base[t] + cnt[t];
    }
  }

#pragma unroll
  for (int k = 0; k < 8; ++k) {
    const int i = t + k * 1024;
    if (i < n) {
      const int rl = (ed[k].x >> 16) & 511;
      const int pos = base[rl] + atomicAdd(&off[rl], 1);
      cv[s + pos] = ed[k];
    }
  }
}

// ============================================================================
// Fused SpMM gather: persistent waves, both supports + bias + relu.
// 4 edge-groups x 16 dim-lanes x 8 dims; group-uniform cv loads; 2x unroll.
// ============================================================================
__global__ __launch_bounds__(256) void spmm_fused_kernel(
    const int* __restrict__ rs_s, const int* __restrict__ rs_e,
    const int2* __restrict__ cv, const unsigned short* __restrict__ preb,
    const float* __restrict__ bias, float* __restrict__ out) {
  const int lane = threadIdx.x & 63;
  const int g = lane >> 4;
  const int dbase = (lane & 15) << 3;
  const int wid = blockIdx.x * 4 + (threadIdx.x >> 6);

  const float4 b0 = *(const float4*)(bias + dbase);
  const float4 b1 = *(const float4*)(bias + dbase + 4);

  for (int row = wid; row < N_NODES; row += SPMM_WAVES) {
    float acc[8];
#pragma unroll
    for (int i = 0; i < 8; ++i) acc[i] = 0.f;

#pragma unroll
    for (int sup = 0; sup < 2; ++sup) {
      const int s = rs_s[sup * N_NODES + row];
      const int e = rs_e[sup * N_NODES + row];
      const unsigned short* pb = preb + (size_t)sup * N_NODES * D;
      int j = s + g;
      for (; j + 4 < e; j += 8) {
        const int2 e0 = cv[j];
        const int2 e1 = cv[j + 4];
        const uint4 q0 = *(const uint4*)(pb + (size_t)(e0.x & 0xFFFF) * D + dbase);
        const uint4 q1 = *(const uint4*)(pb + (size_t)(e1.x & 0xFFFF) * D + dbase);
        const float v0 = __int_as_float(e0.y);
        const float v1 = __int_as_float(e1.y);
        acc[0] = fmaf(v0, __uint_as_float(q0.x << 16), acc[0]);
        acc[1] = fmaf(v0, __uint_as_float(q0.x & 0xFFFF0000u), acc[1]);
        acc[2] = fmaf(v0, __uint_as_float(q0.y << 16), acc[2]);
        acc[3] = fmaf(v0, __uint_as_float(q0.y & 0xFFFF0000u), acc[3]);
        acc[4] = fmaf(v0, __uint_as_float(q0.z << 16), acc[4]);
        acc[5] = fmaf(v0, __uint_as_float(q0.z & 0xFFFF0000u), acc[5]);
        acc[6] = fmaf(v0, __uint_as_float(q0.w << 16), acc[6]);
        acc[7] = fmaf(v0, __uint_as_float(q0.w & 0xFFFF0000u), acc[7]);
        acc[0] = fmaf(v1, __uint_as_float(q1.x << 16), acc[0]);
        acc[1] = fmaf(v1, __uint_as_float(q1.x & 0xFFFF0000u), acc[1]);
        acc[2] = fmaf(v1, __uint_as_float(q1.y << 16), acc[2]);
        acc[3] = fmaf(v1, __uint_as_float(q1.y & 0xFFFF0000u), acc[3]);
        acc[4] = fmaf(v1, __uint_as_float(q1.z << 16), acc[4]);
        acc[5] = fmaf(v1, __uint_as_float(q1.z & 0xFFFF0000u), acc[5]);
        acc[6] = fmaf(v1, __uint_as_float(q1.w << 16), acc[6]);
        acc[7] = fmaf(v1, __uint_as_float(q1.w & 0xFFFF0000u), acc[7]);
      }
      if (j < e) {
        const int2 e0 = cv[j];
        const uint4 q0 = *(const uint4*)(pb + (size_t)(e0.x & 0xFFFF) * D + dbase);
        const float v0 = __int_as_float(e0.y);
        acc[0] = fmaf(v0, __uint_as_float(q0.x << 16), acc[0]);
        acc[1] = fmaf(v0, __uint_as_float(q0.x & 0xFFFF0000u), acc[1]);
        acc[2] = fmaf(v0, __uint_as_float(q0.y << 16), acc[2]);
        acc[3] = fmaf(v0, __uint_as_float(q0.y & 0xFFFF0000u), acc[3]);
        acc[4] = fmaf(v0, __uint_as_float(q0.z << 16), acc[4]);
        acc[5] = fmaf(v0, __uint_as_float(q0.z & 0xFFFF0000u), acc[5]);
        acc[6] = fmaf(v0, __uint_as_float(q0.w << 16), acc[6]);
        acc[7] = fmaf(v0, __uint_as_float(q0.w & 0xFFFF0000u), acc[7]);
      }
    }

#pragma unroll
    for (int i = 0; i < 8; ++i) {
      acc[i] += __shfl_xor(acc[i], 16);
      acc[i] += __shfl_xor(acc[i], 32);
    }

    if (g == 0) {
      float4 r0, r1;
      r0.x = fmaxf(acc[0] + b0.x, 0.f);
      r0.y = fmaxf(acc[1] + b0.y, 0.f);
      r0.z = fmaxf(acc[2] + b0.z, 0.f);
      r0.w = fmaxf(acc[3] + b0.w, 0.f);
      r1.x = fmaxf(acc[4] + b1.x, 0.f);
      r1.y = fmaxf(acc[5] + b1.y, 0.f);
      r1.z = fmaxf(acc[6] + b1.z, 0.f);
      r1.w = fmaxf(acc[7] + b1.w, 0.f);
      float* op = out + (size_t)row * D + dbase;
      *(float4*)op = r0;
      *(float4*)(op + 4) = r1;
    }
  }
}

// ============================================================================
// Fallback: fp32 gemm + atomic scatter (used only if workspace too small)
// ============================================================================
__global__ __launch_bounds__(256) void gemm_f32_kernel(
    const float* __restrict__ x, const float* __restrict__ W,
    float* __restrict__ pre) {
  const int tid = threadIdx.x;
  const int nloc = (tid >> 5) << 3;
  const int d4 = (tid & 31) << 2;
  const int nbase = blockIdx.x * 64;
  __shared__ float xs[64][D];
  {
    float4* xs4 = (float4*)(&xs[0][0]);
    const float4* xg4 = (const float4*)x;
#pragma unroll
    for (int i = 0; i < 8; ++i) {
      const int idx = tid + i * 256;
      const int row = nbase + (idx >> 5);
      xs4[idx] = (row < N_NODES) ? xg4[(size_t)row * 32 + (idx & 31)]
                                 : make_float4(0.f, 0.f, 0.f, 0.f);
    }
  }
  __syncthreads();
  float4 acc[8];
#pragma unroll
  for (int i = 0; i < 8; ++i) acc[i] = make_float4(0.f, 0.f, 0.f, 0.f);
  for (int k = 0; k < D; ++k) {
    const float4 w = *(const float4*)(W + k * D + d4);
#pragma unroll
    for (int i = 0; i < 8; ++i) {
      const float xv = xs[nloc + i][k];
      acc[i].x = fmaf(xv, w.x, acc[i].x);
      acc[i].y = fmaf(xv, w.y, acc[i].y);
      acc[i].z = fmaf(xv, w.z, acc[i].z);
      acc[i].w = fmaf(xv, w.w, acc[i].w);
    }
  }
#pragma unroll
  for (int i = 0; i < 8; ++i) {
    const int n = nbase + nloc + i;
    if (n < N_NODES) *(float4*)(pre + (size_t)n * D + d4) = acc[i];
  }
}

__global__ __launch_bounds__(256) void spmm_scatter_kernel(
    const int* __restrict__ rows, const int* __restrict__ cols,
    const float* __restrict__ vals, const float* __restrict__ pre,
    float* __restrict__ out) {
  const long long idx = (long long)blockIdx.x * blockDim.x + threadIdx.x;
  const int e = (int)(idx >> 6);
  if (e >= N_EDGES) return;
  const int dd = ((int)idx & 63) << 1;
  const int r = rows[e];
  const int c = cols[e];
  const float v = vals[e];
  const float2 p = *(const float2*)(pre + (size_t)c * D + dd);
  float* outp = out + (size_t)r * D + dd;
  atomicAdd(outp + 0, v * p.x);
  atomicAdd(outp + 1, v * p.y);
}

__global__ __launch_bounds__(256) void bias_relu_kernel(
    float* __restrict__ out, const float* __restrict__ b) {
  const int idx = blockIdx.x * blockDim.x + threadIdx.x;
  float4 v = ((float4*)out)[idx];
  const float4 bb = ((const float4*)b)[idx & 31];
  v.x = fmaxf(v.x + bb.x, 0.f);
  v.y = fmaxf(v.y + bb.y, 0.f);
  v.z = fmaxf(v.z + bb.z, 0.f);
  v.w = fmaxf(v.w + bb.w, 0.f);
  ((float4*)out)[idx] = v;
}

extern "C" void kernel_launch(void* const* d_in, const int* in_sizes, int n_in,
                              void* d_out, int out_size, void* d_ws,
                              size_t ws_size, hipStream_t stream) {
  const float* x = (const float*)d_in[0];
  const float* W0 = (const float*)d_in[1];
  const float* W1 = (const float*)d_in[2];
  const float* b = (const float*)d_in[3];
  const int* rows0 = (const int*)d_in[4];
  const int* cols0 = (const int*)d_in[5];
  const float* vals0 = (const float*)d_in[6];
  const int* rows1 = (const int*)d_in[7];
  const int* cols1 = (const int*)d_in[8];
  const float* vals1 = (const float*)d_in[9];
  float* out = (float*)d_out;

  auto align_up = [](size_t v) { return (v + 255) & ~(size_t)255; };
  const size_t PREB = align_up((size_t)2 * N_NODES * D * 2);  // 25.6 MB bf16
  const size_t FILLC = align_up((size_t)NSEG * 4);
  const size_t RS1 = align_up((size_t)2 * N_NODES * 4);  // 400 KB each
  const size_t WPACK = align_up((size_t)2 * D * D * 2);  // 64 KB

  // Tier A: fixed-capacity segments (no hist/scan/memset)
  const size_t CVC = align_up((size_t)NSEG * CAP * 8);  // 12.85 MB
  const size_t NEED_A = PREB + CVC + FILLC + 2 * RS1 + WPACK;  // ~39.4 MB
  // Tier B: exact bases (round-10 path)
  const size_t CV = align_up((size_t)2 * N_EDGES * 8);  // 9.6 MB
  const size_t CNT = align_up((size_t)NSEG * 4);
  const size_t SBSTART = align_up((size_t)(NSEG + 1) * 4);
  const size_t NEED_B = PREB + CV + CNT + FILLC + SBSTART + 2 * RS1 + WPACK;

  char* wsc = (char*)d_ws;

  if (ws_size >= NEED_A) {
    unsigned short* preb = (unsigned short*)wsc;
    int2* cv = (int2*)(wsc + PREB);
    int* fillc = (int*)(wsc + PREB + CVC);
    int* rs_s = (int*)(wsc + PREB + CVC + FILLC);
    int* rs_e = (int*)(wsc + PREB + CVC + FILLC + RS1);
    unsigned short* wpack =
        (unsigned short*)(wsc + PREB + CVC + FILLC + 2 * RS1);

    init_kernel<<<17, 256, 0, stream>>>(W0, W1, wpack, fillc);
    bingemm_kernel<true><<<2 * BIN_BLOCKS + GEMM_BLOCKS, 256, 0, stream>>>(
        rows0, cols0, vals0, rows1, cols1, vals1, fillc, cv, x, wpack, preb);
    sort_kernel<true><<<dim3(SB, 2), 1024, 0, stream>>>(nullptr, fillc, cv,
                                                        rs_s, rs_e);
    spmm_fused_kernel<<<SPMM_BLOCKS, 256, 0, stream>>>(rs_s, rs_e, cv, preb, b,
                                                       out);
  } else if (ws_size >= NEED_B) {
    unsigned short* preb = (unsigned short*)wsc;
    int2* cv = (int2*)(wsc + PREB);
    int* cnt = (int*)(wsc + PREB + CV);
    int* fillc = (int*)(wsc + PREB + CV + CNT);
    int* sbstart = (int*)(wsc + PREB + CV + CNT + FILLC);
    int* rs_s = (int*)(wsc + PREB + CV + CNT + FILLC + SBSTART);
    int* rs_e = (int*)(wsc + PREB + CV + CNT + FILLC + SBSTART + RS1);
    unsigned short* wpack =
        (unsigned short*)(wsc + PREB + CV + CNT + FILLC + SBSTART + 2 * RS1);

    hipMemsetAsync(cnt, 0, (size_t)NSEG * 4, stream);
    histpack_kernel<<<dim3(HIST_BLOCKS + 8, 2), 256, 0, stream>>>(
        rows0, rows1, cnt, W0, W1, wpack);
    scan196_kernel<<<1, 64, 0, stream>>>(cnt, fillc, sbstart);
    bingemm_kernel<false><<<2 * BIN_BLOCKS + GEMM_BLOCKS, 256, 0, stream>>>(
        rows0, cols0, vals0, rows1, cols1, vals1, fillc, cv, x, wpack, preb);
    sort_kernel<false><<<dim3(SB, 2), 1024, 0, stream>>>(sbstart, nullptr, cv,
                                                         rs_s, rs_e);
    spmm_fused_kernel<<<SPMM_BLOCKS, 256, 0, stream>>>(rs_s, rs_e, cv, preb, b,
                                                       out);
  } else {
    float* pre = (float*)wsc;
    hipMemsetAsync(d_out, 0, (size_t)N_NODES * D * 4, stream);
    const int scat_blocks = (N_EDGES * 64 + 255) / 256;
    gemm_f32_kernel<<<GEMM_BLOCKS, 256, 0, stream>>>(x, W0, pre);
    spmm_scatter_kernel<<<scat_blocks, 256, 0, stream>>>(rows0, cols0, vals0,
                                                         pre, out);
    gemm_f32_kernel<<<GEMM_BLOCKS, 256, 0, stream>>>(x, W1, pre);
    spmm_scatter_kernel<<<scat_blocks, 256, 0, stream>>>(rows1, cols1, vals1,
                                                         pre, out);
    bias_relu_kernel<<<(N_NODES * D / 4) / 256, 256, 0, stream>>>(out, b);
  }
}